// Round 7
// baseline (11605.107 us; speedup 1.0000x reference)
//
#include <hip/hip_runtime.h>
#include <stdint.h>

#define STEPS 100

// ---------------------------------------------------------------------------
// Threefry2x32 (JAX-exact, 20 rounds)
// ---------------------------------------------------------------------------
__device__ __forceinline__ uint32_t rotl32(uint32_t v, int r) {
  return (v << r) | (v >> (32 - r));
}

__device__ __forceinline__ void tf2x32(uint32_t k0, uint32_t k1,
                                       uint32_t x0, uint32_t x1,
                                       uint32_t& o0, uint32_t& o1) {
  uint32_t ks2 = k0 ^ k1 ^ 0x1BD11BDAu;
  x0 += k0; x1 += k1;
#define RND(r) { x0 += x1; x1 = rotl32(x1, (r)); x1 ^= x0; }
  RND(13) RND(15) RND(26) RND(6)
  x0 += k1;  x1 += ks2 + 1u;
  RND(17) RND(29) RND(16) RND(24)
  x0 += ks2; x1 += k0 + 2u;
  RND(13) RND(15) RND(26) RND(6)
  x0 += k0;  x1 += k1 + 3u;
  RND(17) RND(29) RND(16) RND(24)
  x0 += k1;  x1 += ks2 + 4u;
  RND(13) RND(15) RND(26) RND(6)
  x0 += ks2; x1 += k0 + 5u;
#undef RND
  o0 = x0; o1 = x1;
}

__global__ void keys_k(uint32_t* __restrict__ kb) {
  int i = threadIdx.x;
  if (i < STEPS) {
    uint32_t a, b;
    tf2x32(0u, 42u, 0u, (uint32_t)i, a, b);
    kb[2 * i] = a;
    kb[2 * i + 1] = b;
  }
}

// wT2 layout [oc][ic][28-pad]: wv loads become 7 aligned float4; the 7
// rp-threads of one oc hit the same cachelines (broadcast).
__global__ void wt_k(const float* __restrict__ w2, float* __restrict__ wT2) {
  int i = blockIdx.x * blockDim.x + threadIdx.x;
  if (i >= 50 * 560) return;
  int oc = i / 560, r = i % 560;
  int ic = r / 28, j = r % 28;
  wT2[i] = (j < 25) ? w2[oc * 500 + ic * 25 + j] : 0.f;
}

// wf0 transpose, padded: wf0T[k*256 + n] = (n<200) ? wf0[n*2450+k] : 0
__global__ void wf0t_k(const float* __restrict__ wf0,
                       float* __restrict__ wf0T) {
  int i = blockIdx.x * blockDim.x + threadIdx.x;
  if (i >= 2450 * 256) return;
  int k = i >> 8, n = i & 255;
  wf0T[i] = (n < 200) ? wf0[n * 2450 + k] : 0.f;
}

// ---------------------------------------------------------------------------
// PERSISTENT per-sample kernel v15: controlled spill to LDS.
// History: the allocator pins this kernel at 128 VGPR regardless of
// __launch_bounds__(512,{1,2,4}) or amdgpu_waves_per_eu(2,2) (v11-v14);
// the ~135-reg live set (m1r[40] persistent + P2's acc28+wv28+u16) spills
// ~13 dwords/thread/step to scratch -> 2.7-3.9 GB HBM write traffic.
// Fix: stop fighting the budget; shrink the live set under 128.
//  * conv1 membranes tt=2,3 (20 floats/thread) live in an LDS stash slab
//    m1stash[512][21] (stride 21: gcd(21,32)=1 -> all banks, 2-way free).
//    Read+write inline in the fire loop: controlled ~6-cyc LDS spill
//    replaces the compiler's ~900-cyc scratch spill. Only tt=0,1 (m1p[20])
//    stay persistent in registers.
//  * phase live sets now: P1 ~75, P2 ~102, P3 ~25 -> fits 128, no spill.
//  * back to proven __launch_bounds__(512,2); everything else = v14.
// Arithmetic per membrane (same adds, same order) unchanged -> bit-identical.
// LDS: 3136+4352+28800+9800+39200+9800+15680+43008 = 153776 B (1 blk/CU).
// ---------------------------------------------------------------------------
__global__ __launch_bounds__(512, 2) void step_all_k(
    const float* __restrict__ x, const float* __restrict__ w1,
    const float* __restrict__ wT2, const uint32_t* __restrict__ kb,
    uint32_t* __restrict__ sp2g) {
  __shared__ __align__(16) float  xhs_l[784];          // x/2 (signed)
  __shared__ __align__(16) float  pois_l[32 * 34];     // padded, zero halo
  __shared__ __align__(16) float  sp1_l[20 * 18 * 20]; // padded, zero halo
  __shared__ int8_t s2_l[50 * 196];                    // conv2 spikes
  __shared__ __align__(16) float  m2_l[50 * 196];      // conv2 membranes
  __shared__ float  m2s_l[2450];                       // pool2 membranes
  __shared__ float  m1s_l[20 * 196];                   // pool1 membranes
  __shared__ float  m1stash[512 * 21];                 // conv1 mem tt=2,3

  const int b  = blockIdx.x;
  const int t  = threadIdx.x;
  // P1 mapping
  const int lq = t & 255;
  const int ohu = __builtin_amdgcn_readfirstlane(t >> 8);
  const bool act1 = lq < 196;
  const int qy = lq / 14, qx = lq % 14;
  // P2 mapping: thread = (oc, row-pair)
  const bool act2 = t < 350;
  const int oc2 = t / 7;              // 0..49
  const int rp  = t % 7;              // 0..6
  const int y0  = 2 * rp;

  for (int p = t; p < 784; p += 512) {
    xhs_l[p] = x[b * 784 + p] * 0.5f;
  }
  // zero padded buffers (halos stay zero forever; data cells rewritten
  // every step before being read)
  for (int i = t; i < 32 * 34; i += 512) pois_l[i] = 0.f;
  for (int i = t; i < 20 * 360; i += 512) sp1_l[i] = 0.f;
  for (int i = t; i < 50 * 196; i += 512) m2_l[i] = 0.f;
  for (int i = t; i < 2450; i += 512) m2s_l[i] = 0.f;
  for (int i = t; i < 20 * 196; i += 512) m1s_l[i] = 0.f;
  for (int i = t; i < 512 * 21; i += 512) m1stash[i] = 0.f;

  // persistent register membranes: conv1 tt=0,1 only (tt=2,3 in m1stash)
  float m1p[2][10];
#pragma unroll
  for (int i = 0; i < 10; ++i) {
    m1p[0][i] = 0.f;
    m1p[1][i] = 0.f;
  }
  __syncthreads();

  // poisson for step 0
  {
    uint32_t k0 = kb[0], k1 = kb[1];
    for (int p = t; p < 784; p += 512) {
      uint32_t o0, o1;
      tf2x32(k0, k1, 0u, (uint32_t)(b * 784 + p), o0, o1);
      float r = __uint_as_float(((o0 ^ o1) >> 9) | 0x3F800000u) - 1.0f;
      float v = xhs_l[p];
      pois_l[(p / 28 + 2) * 34 + (p % 28 + 2)] =
          (fabsf(v) > r) ? ((v > 0.f) ? 1.f : -1.f) : 0.f;
    }
  }
  __syncthreads();

#define LDROW(rr, d) {                                                      \
    const float2* _pr = reinterpret_cast<const float2*>(                    \
        &pois_l[(2 * qy + (rr)) * 34 + 2 * qx]);                            \
    float2 _a0 = _pr[0], _a1 = _pr[1], _a2 = _pr[2];                        \
    d[0] = _a0.x; d[1] = _a0.y; d[2] = _a1.x;                               \
    d[3] = _a1.y; d[4] = _a2.x; d[5] = _a2.y; }

  for (int s = 0; s < STEPS; ++s) {
    // ---- P1: conv1 (10 oc of this half) + fire + pool1 + fire ----
    if (act1) {
      float rA[6], rB[6];
      LDROW(0, rA)
      LDROW(1, rB)
      float acc[4][10];
#pragma unroll
      for (int tt = 0; tt < 4; ++tt)
#pragma unroll
        for (int i = 0; i < 10; ++i) acc[tt][i] = 0.f;
#pragma unroll
      for (int ky = 0; ky < 5; ++ky) {
        // rA = padded row 2qy+ky (rows for tt 0,1), rB = row 2qy+ky+1
#pragma unroll
        for (int kx = 0; kx < 5; ++kx) {
#pragma unroll
          for (int i = 0; i < 10; ++i) {
            float w = w1[(ohu * 10 + i) * 25 + ky * 5 + kx];
            acc[0][i] += w * rA[kx];
            acc[1][i] += w * rA[kx + 1];
            acc[2][i] += w * rB[kx];
            acc[3][i] += w * rB[kx + 1];
          }
        }
        if (ky < 4) {
#pragma unroll
          for (int j = 0; j < 6; ++j) rA[j] = rB[j];
          LDROW(ky + 2, rB)
        }
      }
#pragma unroll
      for (int i = 0; i < 10; ++i) {
        float s4[4];
        // tt = 0,1: register membranes
#pragma unroll
        for (int tt = 0; tt < 2; ++tt) {
          float m = m1p[tt][i] + acc[tt][i];
          float sp = 0.f;
          if (m > 1.0f) { sp = 1.f; m = 0.f; }
          m1p[tt][i] = m;
          s4[tt] = sp;
        }
        // tt = 2,3: LDS-stashed membranes (controlled spill; each thread
        // exclusively owns its 21-float slab -> no races, no barrier dep)
        {
          float m = m1stash[t * 21 + i] + acc[2][i];
          float sp = 0.f;
          if (m > 1.0f) { sp = 1.f; m = 0.f; }
          m1stash[t * 21 + i] = m;
          s4[2] = sp;
        }
        {
          float m = m1stash[t * 21 + 10 + i] + acc[3][i];
          float sp = 0.f;
          if (m > 1.0f) { sp = 1.f; m = 0.f; }
          m1stash[t * 21 + 10 + i] = m;
          s4[3] = sp;
        }
        float a = 0.25f * (((s4[0] + s4[1]) + s4[2]) + s4[3]);
        int mi = (ohu * 10 + i) * 196 + lq;
        float mm = m1s_l[mi] + a;
        float spp = 0.f;
        if (mm > 0.75f) { spp = 1.f; mm = 0.f; }
        m1s_l[mi] = mm;
        sp1_l[(ohu * 10 + i) * 360 + (qy + 2) * 20 + (qx + 2)] = spp;
      }
    }
    __syncthreads();

    // ---- P2: conv2, float4 weights + padded vec4 u-rows ----
    if (act2) {
      float acc[2][14];
#pragma unroll
      for (int r = 0; r < 2; ++r)
#pragma unroll
        for (int xx = 0; xx < 14; ++xx) acc[r][xx] = 0.f;
      const float4* wbase =
          reinterpret_cast<const float4*>(wT2 + oc2 * 560);
#pragma unroll 1
      for (int ic = 0; ic < 20; ++ic) {
        float wv[28];
#pragma unroll
        for (int j = 0; j < 7; ++j) {
          float4 q = wbase[ic * 7 + j];
          wv[4 * j]     = q.x;
          wv[4 * j + 1] = q.y;
          wv[4 * j + 2] = q.z;
          wv[4 * j + 3] = q.w;
        }
        const float* spi = sp1_l + ic * 360;
#pragma unroll
        for (int jr = 0; jr < 6; ++jr) {
          const float4* rp4 =
              reinterpret_cast<const float4*>(spi + (y0 + jr) * 20);
          float4 rv0 = rp4[0], rv1 = rp4[1], rv2 = rp4[2], rv3 = rp4[3];
          float u[16];
          u[0]  = rv0.x; u[1]  = rv0.y; u[2]  = rv0.z; u[3]  = rv0.w;
          u[4]  = rv1.x; u[5]  = rv1.y; u[6]  = rv1.z; u[7]  = rv1.w;
          u[8]  = rv2.x; u[9]  = rv2.y; u[10] = rv2.z; u[11] = rv2.w;
          u[12] = rv3.x; u[13] = rv3.y; u[14] = rv3.z; u[15] = rv3.w;
          // cols 16,17 are padded zeros: their FMAs are dropped (bit-safe)
          if (jr < 5) {                 // r=0, ky=jr
#pragma unroll
            for (int kx = 0; kx < 5; ++kx) {
              float w = wv[jr * 5 + kx];
#pragma unroll
              for (int xx = 0; xx < 14; ++xx)
                if (xx + kx < 16) acc[0][xx] += w * u[xx + kx];
            }
          }
          if (jr >= 1) {                // r=1, ky=jr-1
#pragma unroll
            for (int kx = 0; kx < 5; ++kx) {
              float w = wv[(jr - 1) * 5 + kx];
#pragma unroll
              for (int xx = 0; xx < 14; ++xx)
                if (xx + kx < 16) acc[1][xx] += w * u[xx + kx];
            }
          }
        }
      }
#pragma unroll
      for (int r = 0; r < 2; ++r) {
        int y = y0 + r;
#pragma unroll
        for (int xx = 0; xx < 14; ++xx) {
          int li = oc2 * 196 + y * 14 + xx;
          float m = m2_l[li] + acc[r][xx];
          int8_t sp = 0;
          if (m > 1.0f) { sp = 1; m = 0.f; }
          m2_l[li] = m;
          s2_l[li] = sp;
        }
      }
    }
    __syncthreads();

    // ---- P3: pool2 + fire -> ballot pack, + poisson(s+1) ----
#pragma unroll
    for (int i = 0; i < 5; ++i) {
      int e = i * 512 + t;
      bool fire = false;
      if (e < 2450) {
        int oc = e / 49, qq = e % 49;
        int yo = qq / 7, xo = qq % 7;
        int ib = oc * 196 + 2 * yo * 14 + 2 * xo;
        float s00 = (float)s2_l[ib];
        float s01 = (float)s2_l[ib + 1];
        float s10 = (float)s2_l[ib + 14];
        float s11 = (float)s2_l[ib + 15];
        float a = 0.25f * (((s00 + s01) + s10) + s11);
        float m = m2s_l[e] + a;
        if (m > 0.75f) { fire = true; m = 0.f; }
        m2s_l[e] = m;
      }
      unsigned long long mask = __ballot(fire);
      int base = (e & ~63);
      if ((t & 63) == 0 && base < 2450) {
        int d = base >> 5;
        sp2g[b * 7700 + s * 77 + d] = (uint32_t)mask;
        if (base + 32 < 2450)
          sp2g[b * 7700 + s * 77 + d + 1] = (uint32_t)(mask >> 32);
      }
    }
    if (s + 1 < STEPS) {
      uint32_t k0 = kb[2 * (s + 1)], k1 = kb[2 * (s + 1) + 1];
      for (int p = t; p < 784; p += 512) {
        uint32_t o0, o1;
        tf2x32(k0, k1, 0u, (uint32_t)(b * 784 + p), o0, o1);
        float r = __uint_as_float(((o0 ^ o1) >> 9) | 0x3F800000u) - 1.0f;
        float v = xhs_l[p];
        pois_l[(p / 28 + 2) * 34 + (p % 28 + 2)] =
            (fabsf(v) > r) ? ((v > 0.f) ? 1.f : -1.f) : 0.f;
      }
    }
    __syncthreads();
  }
#undef LDROW
}

// ---------------------------------------------------------------------------
// fc0 (R14-proven): block = sample, lane = neuron; wave-uniform ctz over
// spike bits; acc += wf0T[k][n] coalesced; k ascending -> bit-identical.
// ---------------------------------------------------------------------------
__global__ __launch_bounds__(256) void fc0f_k(
    const uint32_t* __restrict__ sp2g, const float* __restrict__ wf0T,
    float* __restrict__ Tf0g) {
  __shared__ uint32_t mk[77];
  const int b = blockIdx.x;
  const int n = threadIdx.x;
  float m = 0.f, T = 0.f;
  for (int s = 0; s < STEPS; ++s) {
    __syncthreads();
    if (n < 77) mk[n] = sp2g[b * 7700 + s * 77 + n];
    __syncthreads();
    float acc = 0.f;
    for (int d = 0; d < 77; ++d) {
      uint32_t um = mk[d];
      while (um) {
        int j = __builtin_ctz(um);
        um &= um - 1;
        acc += wf0T[((d << 5) + j) * 256 + n];
      }
    }
    m += acc;
    if (m > 1.0f) { T += 1.f; m = 0.f; }
  }
  if (n < 200) Tf0g[b * 200 + n] = T;
}

// ---------------------------------------------------------------------------
// final: out[b][i] = (Tf0[b][:] . wf1[i][:]) / 1 / 100   (j ascending)
// ---------------------------------------------------------------------------
__global__ void fc1_k(const float* __restrict__ Tf0,
                      const float* __restrict__ wf1,
                      float* __restrict__ out) {
  int idx = blockIdx.x * blockDim.x + threadIdx.x;
  if (idx >= 5120) return;
  int b = idx / 10, i = idx % 10;
  float a = 0.f;
  for (int j = 0; j < 200; ++j) a += Tf0[b * 200 + j] * wf1[i * 200 + j];
  out[idx] = (a / 1.0f) / 100.0f;
}

// ---------------------------------------------------------------------------
extern "C" void kernel_launch(void* const* d_in, const int* in_sizes, int n_in,
                              void* d_out, int out_size, void* d_ws, size_t ws_size,
                              hipStream_t stream) {
  (void)in_sizes; (void)n_in; (void)out_size; (void)ws_size;
  const float* x   = (const float*)d_in[0];
  const float* w1  = (const float*)d_in[1];
  const float* w2  = (const float*)d_in[2];
  const float* wf0 = (const float*)d_in[3];
  const float* wf1 = (const float*)d_in[4];
  float* out = (float*)d_out;
  char* ws = (char*)d_ws;

  // workspace: Tf0 | wT2 | keys | wf0T | sp2 bitmask  (~18.9 MB)
  const size_t tf0_b  = 512ull * 200 * 4;
  const size_t wt_b   = 50ull * 560 * 4;   // 112000 B
  const size_t key_b  = 1024;
  const size_t wf0t_b = 2450ull * 256 * 4;
  float*    Tf0g = (float*)ws;
  float*    wT2  = (float*)(ws + tf0_b);
  uint32_t* kb   = (uint32_t*)(ws + tf0_b + wt_b);
  float*    wf0T = (float*)(ws + tf0_b + wt_b + key_b);
  uint32_t* sp2g = (uint32_t*)(ws + tf0_b + wt_b + key_b + wf0t_b);

  keys_k<<<1, 128, 0, stream>>>(kb);
  wt_k<<<110, 256, 0, stream>>>(w2, wT2);
  wf0t_k<<<2450, 256, 0, stream>>>(wf0, wf0T);
  step_all_k<<<512, 512, 0, stream>>>(x, w1, wT2, kb, sp2g);
  fc0f_k<<<512, 256, 0, stream>>>(sp2g, wf0T, Tf0g);
  fc1_k<<<20, 256, 0, stream>>>(Tf0g, wf1, out);
}

// Round 8
// 11102.328 us; speedup vs baseline: 1.0453x; 1.0453x over previous
//
#include <hip/hip_runtime.h>
#include <stdint.h>

#define STEPS 100

// ---------------------------------------------------------------------------
// Threefry2x32 (JAX-exact, 20 rounds)
// ---------------------------------------------------------------------------
__device__ __forceinline__ uint32_t rotl32(uint32_t v, int r) {
  return (v << r) | (v >> (32 - r));
}

__device__ __forceinline__ void tf2x32(uint32_t k0, uint32_t k1,
                                       uint32_t x0, uint32_t x1,
                                       uint32_t& o0, uint32_t& o1) {
  uint32_t ks2 = k0 ^ k1 ^ 0x1BD11BDAu;
  x0 += k0; x1 += k1;
#define RND(r) { x0 += x1; x1 = rotl32(x1, (r)); x1 ^= x0; }
  RND(13) RND(15) RND(26) RND(6)
  x0 += k1;  x1 += ks2 + 1u;
  RND(17) RND(29) RND(16) RND(24)
  x0 += ks2; x1 += k0 + 2u;
  RND(13) RND(15) RND(26) RND(6)
  x0 += k0;  x1 += k1 + 3u;
  RND(17) RND(29) RND(16) RND(24)
  x0 += k1;  x1 += ks2 + 4u;
  RND(13) RND(15) RND(26) RND(6)
  x0 += ks2; x1 += k0 + 5u;
#undef RND
  o0 = x0; o1 = x1;
}

__global__ void keys_k(uint32_t* __restrict__ kb) {
  int i = threadIdx.x;
  if (i < STEPS) {
    uint32_t a, b;
    tf2x32(0u, 42u, 0u, (uint32_t)i, a, b);
    kb[2 * i] = a;
    kb[2 * i + 1] = b;
  }
}

// wT2 layout [oc][ic][28-pad]: wv loads become 7 aligned float4; the 7
// rp-threads of one oc hit the same cachelines (broadcast).
__global__ void wt_k(const float* __restrict__ w2, float* __restrict__ wT2) {
  int i = blockIdx.x * blockDim.x + threadIdx.x;
  if (i >= 50 * 560) return;
  int oc = i / 560, r = i % 560;
  int ic = r / 28, j = r % 28;
  wT2[i] = (j < 25) ? w2[oc * 500 + ic * 25 + j] : 0.f;
}

// wf0 transpose, padded: wf0T[k*256 + n] = (n<200) ? wf0[n*2450+k] : 0
__global__ void wf0t_k(const float* __restrict__ wf0,
                       float* __restrict__ wf0T) {
  int i = blockIdx.x * blockDim.x + threadIdx.x;
  if (i >= 2450 * 256) return;
  int k = i >> 8, n = i & 255;
  wf0T[i] = (n < 200) ? wf0[n * 2450 + k] : 0.f;
}

// ---------------------------------------------------------------------------
// P2 row FMA block: JR static -> all indices compile-time (rule #20).
// Order per output: r0 block before r1 block, kx ascending -> identical to
// the original per-jr body.
// ---------------------------------------------------------------------------
template <int JR>
__device__ __forceinline__ void p2row(const float4& q0, const float4& q1,
                                      const float4& q2, const float4& q3,
                                      const float* wv, float (&acc)[2][14]) {
  float u[16] = {q0.x, q0.y, q0.z, q0.w, q1.x, q1.y, q1.z, q1.w,
                 q2.x, q2.y, q2.z, q2.w, q3.x, q3.y, q3.z, q3.w};
  if (JR < 5) {                        // r=0, ky=JR
#pragma unroll
    for (int kx = 0; kx < 5; ++kx) {
      float w = wv[JR * 5 + kx];
#pragma unroll
      for (int xx = 0; xx < 14; ++xx)
        if (xx + kx < 16) acc[0][xx] += w * u[xx + kx];
    }
  }
  if (JR >= 1) {                       // r=1, ky=JR-1
#pragma unroll
    for (int kx = 0; kx < 5; ++kx) {
      float w = wv[(JR - 1) * 5 + kx];
#pragma unroll
      for (int xx = 0; xx < 14; ++xx)
        if (xx + kx < 16) acc[1][xx] += w * u[xx + kx];
    }
  }
}

// ---------------------------------------------------------------------------
// PERSISTENT per-sample kernel v16: bound P2's live row set.
// v15's residual 0.96 GB scratch-write = the fully-unrolled jr loop: the
// compiler SSA-renames and hoists all 24 ds_read_b128 row loads to the ic
// loop head (96 live floats instead of 16) -> peak live ~150 > 128 cap ->
// ~13 dwords/thread/step spilled. Fix: explicit 2-buffer (A/B) software
// pipeline over the 6 rows, with sched_barrier(0) between segments so the
// scheduler cannot re-hoist later loads across earlier FMA blocks. Each
// segment: 4 ds_read_b128 (next row) issued alongside 134 FMAs (current
// row) -> latency hidden, peak live ~120 < 128.
// Everything else = v15 (stash for conv1 tt=2,3 membranes, bank-safe
// strides 20/34, float4 weights). Per-output summation order (ic asc,
// jr/ky asc, r0-before-r1, kx asc) unchanged -> bit-identical output.
// ---------------------------------------------------------------------------
__global__ __launch_bounds__(512, 2) void step_all_k(
    const float* __restrict__ x, const float* __restrict__ w1,
    const float* __restrict__ wT2, const uint32_t* __restrict__ kb,
    uint32_t* __restrict__ sp2g) {
  __shared__ __align__(16) float  xhs_l[784];          // x/2 (signed)
  __shared__ __align__(16) float  pois_l[32 * 34];     // padded, zero halo
  __shared__ __align__(16) float  sp1_l[20 * 18 * 20]; // padded, zero halo
  __shared__ int8_t s2_l[50 * 196];                    // conv2 spikes
  __shared__ __align__(16) float  m2_l[50 * 196];      // conv2 membranes
  __shared__ float  m2s_l[2450];                       // pool2 membranes
  __shared__ float  m1s_l[20 * 196];                   // pool1 membranes
  __shared__ float  m1stash[512 * 21];                 // conv1 mem tt=2,3

  const int b  = blockIdx.x;
  const int t  = threadIdx.x;
  // P1 mapping
  const int lq = t & 255;
  const int ohu = __builtin_amdgcn_readfirstlane(t >> 8);
  const bool act1 = lq < 196;
  const int qy = lq / 14, qx = lq % 14;
  // P2 mapping: thread = (oc, row-pair)
  const bool act2 = t < 350;
  const int oc2 = t / 7;              // 0..49
  const int rp  = t % 7;              // 0..6
  const int y0  = 2 * rp;

  for (int p = t; p < 784; p += 512) {
    xhs_l[p] = x[b * 784 + p] * 0.5f;
  }
  // zero padded buffers (halos stay zero forever; data cells rewritten
  // every step before being read)
  for (int i = t; i < 32 * 34; i += 512) pois_l[i] = 0.f;
  for (int i = t; i < 20 * 360; i += 512) sp1_l[i] = 0.f;
  for (int i = t; i < 50 * 196; i += 512) m2_l[i] = 0.f;
  for (int i = t; i < 2450; i += 512) m2s_l[i] = 0.f;
  for (int i = t; i < 20 * 196; i += 512) m1s_l[i] = 0.f;
  for (int i = t; i < 512 * 21; i += 512) m1stash[i] = 0.f;

  // persistent register membranes: conv1 tt=0,1 only (tt=2,3 in m1stash)
  float m1p[2][10];
#pragma unroll
  for (int i = 0; i < 10; ++i) {
    m1p[0][i] = 0.f;
    m1p[1][i] = 0.f;
  }
  __syncthreads();

  // poisson for step 0
  {
    uint32_t k0 = kb[0], k1 = kb[1];
    for (int p = t; p < 784; p += 512) {
      uint32_t o0, o1;
      tf2x32(k0, k1, 0u, (uint32_t)(b * 784 + p), o0, o1);
      float r = __uint_as_float(((o0 ^ o1) >> 9) | 0x3F800000u) - 1.0f;
      float v = xhs_l[p];
      pois_l[(p / 28 + 2) * 34 + (p % 28 + 2)] =
          (fabsf(v) > r) ? ((v > 0.f) ? 1.f : -1.f) : 0.f;
    }
  }
  __syncthreads();

#define LDROW(rr, d) {                                                      \
    const float2* _pr = reinterpret_cast<const float2*>(                    \
        &pois_l[(2 * qy + (rr)) * 34 + 2 * qx]);                            \
    float2 _a0 = _pr[0], _a1 = _pr[1], _a2 = _pr[2];                        \
    d[0] = _a0.x; d[1] = _a0.y; d[2] = _a1.x;                               \
    d[3] = _a1.y; d[4] = _a2.x; d[5] = _a2.y; }

  for (int s = 0; s < STEPS; ++s) {
    // ---- P1: conv1 (10 oc of this half) + fire + pool1 + fire ----
    if (act1) {
      float rA[6], rB[6];
      LDROW(0, rA)
      LDROW(1, rB)
      float acc[4][10];
#pragma unroll
      for (int tt = 0; tt < 4; ++tt)
#pragma unroll
        for (int i = 0; i < 10; ++i) acc[tt][i] = 0.f;
#pragma unroll
      for (int ky = 0; ky < 5; ++ky) {
        // rA = padded row 2qy+ky (rows for tt 0,1), rB = row 2qy+ky+1
#pragma unroll
        for (int kx = 0; kx < 5; ++kx) {
#pragma unroll
          for (int i = 0; i < 10; ++i) {
            float w = w1[(ohu * 10 + i) * 25 + ky * 5 + kx];
            acc[0][i] += w * rA[kx];
            acc[1][i] += w * rA[kx + 1];
            acc[2][i] += w * rB[kx];
            acc[3][i] += w * rB[kx + 1];
          }
        }
        if (ky < 4) {
#pragma unroll
          for (int j = 0; j < 6; ++j) rA[j] = rB[j];
          LDROW(ky + 2, rB)
        }
      }
#pragma unroll
      for (int i = 0; i < 10; ++i) {
        float s4[4];
        // tt = 0,1: register membranes
#pragma unroll
        for (int tt = 0; tt < 2; ++tt) {
          float m = m1p[tt][i] + acc[tt][i];
          float sp = 0.f;
          if (m > 1.0f) { sp = 1.f; m = 0.f; }
          m1p[tt][i] = m;
          s4[tt] = sp;
        }
        // tt = 2,3: LDS-stashed membranes (controlled spill; each thread
        // exclusively owns its 21-float slab -> no races, no barrier dep)
        {
          float m = m1stash[t * 21 + i] + acc[2][i];
          float sp = 0.f;
          if (m > 1.0f) { sp = 1.f; m = 0.f; }
          m1stash[t * 21 + i] = m;
          s4[2] = sp;
        }
        {
          float m = m1stash[t * 21 + 10 + i] + acc[3][i];
          float sp = 0.f;
          if (m > 1.0f) { sp = 1.f; m = 0.f; }
          m1stash[t * 21 + 10 + i] = m;
          s4[3] = sp;
        }
        float a = 0.25f * (((s4[0] + s4[1]) + s4[2]) + s4[3]);
        int mi = (ohu * 10 + i) * 196 + lq;
        float mm = m1s_l[mi] + a;
        float spp = 0.f;
        if (mm > 0.75f) { spp = 1.f; mm = 0.f; }
        m1s_l[mi] = mm;
        sp1_l[(ohu * 10 + i) * 360 + (qy + 2) * 20 + (qx + 2)] = spp;
      }
    }
    __syncthreads();

    // ---- P2: conv2, 2-buffer rolling row pipeline (A/B) ----
    if (act2) {
      float acc[2][14];
#pragma unroll
      for (int r = 0; r < 2; ++r)
#pragma unroll
        for (int xx = 0; xx < 14; ++xx) acc[r][xx] = 0.f;
      const float4* wbase =
          reinterpret_cast<const float4*>(wT2 + oc2 * 560);
#pragma unroll 1
      for (int ic = 0; ic < 20; ++ic) {
        float wv[28];
#pragma unroll
        for (int j = 0; j < 7; ++j) {
          float4 q = wbase[ic * 7 + j];
          wv[4 * j]     = q.x;
          wv[4 * j + 1] = q.y;
          wv[4 * j + 2] = q.z;
          wv[4 * j + 3] = q.w;
        }
        const float* spi = sp1_l + ic * 360;
        float4 a0, a1, a2, a3, b0, b1, b2, b3;
        {
          const float4* rn = reinterpret_cast<const float4*>(spi + y0 * 20);
          a0 = rn[0]; a1 = rn[1]; a2 = rn[2]; a3 = rn[3];
        }
        {
          const float4* rn =
              reinterpret_cast<const float4*>(spi + (y0 + 1) * 20);
          b0 = rn[0]; b1 = rn[1]; b2 = rn[2]; b3 = rn[3];
        }
        p2row<0>(a0, a1, a2, a3, wv, acc);
        {
          const float4* rn =
              reinterpret_cast<const float4*>(spi + (y0 + 2) * 20);
          a0 = rn[0]; a1 = rn[1]; a2 = rn[2]; a3 = rn[3];
        }
        __builtin_amdgcn_sched_barrier(0);
        p2row<1>(b0, b1, b2, b3, wv, acc);
        {
          const float4* rn =
              reinterpret_cast<const float4*>(spi + (y0 + 3) * 20);
          b0 = rn[0]; b1 = rn[1]; b2 = rn[2]; b3 = rn[3];
        }
        __builtin_amdgcn_sched_barrier(0);
        p2row<2>(a0, a1, a2, a3, wv, acc);
        {
          const float4* rn =
              reinterpret_cast<const float4*>(spi + (y0 + 4) * 20);
          a0 = rn[0]; a1 = rn[1]; a2 = rn[2]; a3 = rn[3];
        }
        __builtin_amdgcn_sched_barrier(0);
        p2row<3>(b0, b1, b2, b3, wv, acc);
        {
          const float4* rn =
              reinterpret_cast<const float4*>(spi + (y0 + 5) * 20);
          b0 = rn[0]; b1 = rn[1]; b2 = rn[2]; b3 = rn[3];
        }
        __builtin_amdgcn_sched_barrier(0);
        p2row<4>(a0, a1, a2, a3, wv, acc);
        p2row<5>(b0, b1, b2, b3, wv, acc);
      }
#pragma unroll
      for (int r = 0; r < 2; ++r) {
        int y = y0 + r;
#pragma unroll
        for (int xx = 0; xx < 14; ++xx) {
          int li = oc2 * 196 + y * 14 + xx;
          float m = m2_l[li] + acc[r][xx];
          int8_t sp = 0;
          if (m > 1.0f) { sp = 1; m = 0.f; }
          m2_l[li] = m;
          s2_l[li] = sp;
        }
      }
    }
    __syncthreads();

    // ---- P3: pool2 + fire -> ballot pack, + poisson(s+1) ----
#pragma unroll
    for (int i = 0; i < 5; ++i) {
      int e = i * 512 + t;
      bool fire = false;
      if (e < 2450) {
        int oc = e / 49, qq = e % 49;
        int yo = qq / 7, xo = qq % 7;
        int ib = oc * 196 + 2 * yo * 14 + 2 * xo;
        float s00 = (float)s2_l[ib];
        float s01 = (float)s2_l[ib + 1];
        float s10 = (float)s2_l[ib + 14];
        float s11 = (float)s2_l[ib + 15];
        float a = 0.25f * (((s00 + s01) + s10) + s11);
        float m = m2s_l[e] + a;
        if (m > 0.75f) { fire = true; m = 0.f; }
        m2s_l[e] = m;
      }
      unsigned long long mask = __ballot(fire);
      int base = (e & ~63);
      if ((t & 63) == 0 && base < 2450) {
        int d = base >> 5;
        sp2g[b * 7700 + s * 77 + d] = (uint32_t)mask;
        if (base + 32 < 2450)
          sp2g[b * 7700 + s * 77 + d + 1] = (uint32_t)(mask >> 32);
      }
    }
    if (s + 1 < STEPS) {
      uint32_t k0 = kb[2 * (s + 1)], k1 = kb[2 * (s + 1) + 1];
      for (int p = t; p < 784; p += 512) {
        uint32_t o0, o1;
        tf2x32(k0, k1, 0u, (uint32_t)(b * 784 + p), o0, o1);
        float r = __uint_as_float(((o0 ^ o1) >> 9) | 0x3F800000u) - 1.0f;
        float v = xhs_l[p];
        pois_l[(p / 28 + 2) * 34 + (p % 28 + 2)] =
            (fabsf(v) > r) ? ((v > 0.f) ? 1.f : -1.f) : 0.f;
      }
    }
    __syncthreads();
  }
#undef LDROW
}

// ---------------------------------------------------------------------------
// fc0 (R14-proven): block = sample, lane = neuron; wave-uniform ctz over
// spike bits; acc += wf0T[k][n] coalesced; k ascending -> bit-identical.
// ---------------------------------------------------------------------------
__global__ __launch_bounds__(256) void fc0f_k(
    const uint32_t* __restrict__ sp2g, const float* __restrict__ wf0T,
    float* __restrict__ Tf0g) {
  __shared__ uint32_t mk[77];
  const int b = blockIdx.x;
  const int n = threadIdx.x;
  float m = 0.f, T = 0.f;
  for (int s = 0; s < STEPS; ++s) {
    __syncthreads();
    if (n < 77) mk[n] = sp2g[b * 7700 + s * 77 + n];
    __syncthreads();
    float acc = 0.f;
    for (int d = 0; d < 77; ++d) {
      uint32_t um = mk[d];
      while (um) {
        int j = __builtin_ctz(um);
        um &= um - 1;
        acc += wf0T[((d << 5) + j) * 256 + n];
      }
    }
    m += acc;
    if (m > 1.0f) { T += 1.f; m = 0.f; }
  }
  if (n < 200) Tf0g[b * 200 + n] = T;
}

// ---------------------------------------------------------------------------
// final: out[b][i] = (Tf0[b][:] . wf1[i][:]) / 1 / 100   (j ascending)
// ---------------------------------------------------------------------------
__global__ void fc1_k(const float* __restrict__ Tf0,
                      const float* __restrict__ wf1,
                      float* __restrict__ out) {
  int idx = blockIdx.x * blockDim.x + threadIdx.x;
  if (idx >= 5120) return;
  int b = idx / 10, i = idx % 10;
  float a = 0.f;
  for (int j = 0; j < 200; ++j) a += Tf0[b * 200 + j] * wf1[i * 200 + j];
  out[idx] = (a / 1.0f) / 100.0f;
}

// ---------------------------------------------------------------------------
extern "C" void kernel_launch(void* const* d_in, const int* in_sizes, int n_in,
                              void* d_out, int out_size, void* d_ws, size_t ws_size,
                              hipStream_t stream) {
  (void)in_sizes; (void)n_in; (void)out_size; (void)ws_size;
  const float* x   = (const float*)d_in[0];
  const float* w1  = (const float*)d_in[1];
  const float* w2  = (const float*)d_in[2];
  const float* wf0 = (const float*)d_in[3];
  const float* wf1 = (const float*)d_in[4];
  float* out = (float*)d_out;
  char* ws = (char*)d_ws;

  // workspace: Tf0 | wT2 | keys | wf0T | sp2 bitmask  (~18.9 MB)
  const size_t tf0_b  = 512ull * 200 * 4;
  const size_t wt_b   = 50ull * 560 * 4;   // 112000 B
  const size_t key_b  = 1024;
  const size_t wf0t_b = 2450ull * 256 * 4;
  float*    Tf0g = (float*)ws;
  float*    wT2  = (float*)(ws + tf0_b);
  uint32_t* kb   = (uint32_t*)(ws + tf0_b + wt_b);
  float*    wf0T = (float*)(ws + tf0_b + wt_b + key_b);
  uint32_t* sp2g = (uint32_t*)(ws + tf0_b + wt_b + key_b + wf0t_b);

  keys_k<<<1, 128, 0, stream>>>(kb);
  wt_k<<<110, 256, 0, stream>>>(w2, wT2);
  wf0t_k<<<2450, 256, 0, stream>>>(wf0, wf0T);
  step_all_k<<<512, 512, 0, stream>>>(x, w1, wT2, kb, sp2g);
  fc0f_k<<<512, 256, 0, stream>>>(sp2g, wf0T, Tf0g);
  fc1_k<<<20, 256, 0, stream>>>(Tf0g, wf1, out);
}

// Round 9
// 10375.282 us; speedup vs baseline: 1.1185x; 1.0701x over previous
//
#include <hip/hip_runtime.h>
#include <stdint.h>

#define STEPS 100

typedef float f2 __attribute__((ext_vector_type(2)));

// ---------------------------------------------------------------------------
// Threefry2x32 (JAX-exact, 20 rounds)
// ---------------------------------------------------------------------------
__device__ __forceinline__ uint32_t rotl32(uint32_t v, int r) {
  return (v << r) | (v >> (32 - r));
}

__device__ __forceinline__ void tf2x32(uint32_t k0, uint32_t k1,
                                       uint32_t x0, uint32_t x1,
                                       uint32_t& o0, uint32_t& o1) {
  uint32_t ks2 = k0 ^ k1 ^ 0x1BD11BDAu;
  x0 += k0; x1 += k1;
#define RND(r) { x0 += x1; x1 = rotl32(x1, (r)); x1 ^= x0; }
  RND(13) RND(15) RND(26) RND(6)
  x0 += k1;  x1 += ks2 + 1u;
  RND(17) RND(29) RND(16) RND(24)
  x0 += ks2; x1 += k0 + 2u;
  RND(13) RND(15) RND(26) RND(6)
  x0 += k0;  x1 += k1 + 3u;
  RND(17) RND(29) RND(16) RND(24)
  x0 += k1;  x1 += ks2 + 4u;
  RND(13) RND(15) RND(26) RND(6)
  x0 += ks2; x1 += k0 + 5u;
#undef RND
  o0 = x0; o1 = x1;
}

__global__ void keys_k(uint32_t* __restrict__ kb) {
  int i = threadIdx.x;
  if (i < STEPS) {
    uint32_t a, b;
    tf2x32(0u, 42u, 0u, (uint32_t)i, a, b);
    kb[2 * i] = a;
    kb[2 * i + 1] = b;
  }
}

// wT3: row-PAIRED weights for v_pk_fma_f32.
// Layout [oc][ic][jr][12]: jr slot = 5 float2 pairs (10 floats) + 2 pad.
// pair[kx] = (lo = w[jr][kx] if jr<5 else 0,  hi = w[jr-1][kx] if jr>=1
// else 0). Slot stride 48B -> every jr slot 16B-aligned.
__global__ void wt3_k(const float* __restrict__ w2, float* __restrict__ wT3) {
  int i = blockIdx.x * blockDim.x + threadIdx.x;
  if (i >= 50 * 20 * 72) return;
  int oc = i / 1440, r = i % 1440;
  int ic = r / 72, q = r % 72;
  int jr = q / 12, p = q % 12;
  float v = 0.f;
  if (p < 10) {
    int kx = p >> 1, h = p & 1;
    if (h == 0 && jr < 5)  v = w2[oc * 500 + ic * 25 + jr * 5 + kx];
    if (h == 1 && jr >= 1) v = w2[oc * 500 + ic * 25 + (jr - 1) * 5 + kx];
  }
  wT3[i] = v;
}

// wf0 transpose, padded: wf0T[k*256 + n] = (n<200) ? wf0[n*2450+k] : 0
__global__ void wf0t_k(const float* __restrict__ wf0,
                       float* __restrict__ wf0T) {
  int i = blockIdx.x * blockDim.x + threadIdx.x;
  if (i >= 2450 * 256) return;
  int k = i >> 8, n = i & 255;
  wf0T[i] = (n < 200) ? wf0[n * 2450 + k] : 0.f;
}

// ---------------------------------------------------------------------------
// P2 packed-FMA block: both output rows of the pair advance together via
// f2 (v_pk_fma_f32). Per output the term sequence (kx asc; caller supplies
// jr asc, ic asc) is the same IEEE-FMA chain as the scalar version; the
// edge half-pairs multiply exact 0 by u>=0 -> +0 -> no-op (acc is never -0
// when built from +0 by adds). Bit-identical.
// ---------------------------------------------------------------------------
__device__ __forceinline__ void p2blk(const float4& q0, const float4& q1,
                                      const float4& q2, const float4& q3,
                                      const f2* wp, f2* acc2) {
  float u[18] = {q0.x, q0.y, q0.z, q0.w, q1.x, q1.y, q1.z, q1.w,
                 q2.x, q2.y, q2.z, q2.w, q3.x, q3.y, q3.z, q3.w, 0.f, 0.f};
#pragma unroll
  for (int kx = 0; kx < 5; ++kx) {
    f2 w = wp[kx];
#pragma unroll
    for (int xx = 0; xx < 14; ++xx) {
      f2 us = {u[xx + kx], u[xx + kx]};
      acc2[xx] = __builtin_elementwise_fma(w, us, acc2[xx]);
    }
  }
}

__device__ __forceinline__ void ldwp(const float* wic, int jr, f2* wp) {
  const float4* p = reinterpret_cast<const float4*>(wic + jr * 12);
  float4 a = p[0], b = p[1];
  float2 c = *reinterpret_cast<const float2*>(wic + jr * 12 + 8);
  wp[0] = f2{a.x, a.y}; wp[1] = f2{a.z, a.w};
  wp[2] = f2{b.x, b.y}; wp[3] = f2{b.z, b.w};
  wp[4] = f2{c.x, c.y};
}

// ---------------------------------------------------------------------------
// PERSISTENT per-sample kernel v17: packed-fp32 conv2.
// v16 killed the spill (WRITE 15.4 MB baseline) -> kernel is VALU-issue
// bound (busiest SIMD ~57K cyc of P2 FMA issue per block-step). Halve the
// FMA stream with v_pk_fma_f32: acc2[xx] = (r0,r1) pair; weights pre-
// paired in wT3 (edge rows padded with exact-no-op zeros); u broadcast.
// ~640 scalar FMA/ic -> 420 pk (+11 VMEM). A/B row+weight double-buffer
// with sched_barrier(0) fencing kept from v16 (prevents the load-hoist
// that caused the v15 spill). Everything else = v16.
// Per-output FMA chain (ic asc, jr/ky asc, kx asc) unchanged ->
// bit-identical output.
// ---------------------------------------------------------------------------
__global__ __launch_bounds__(512, 2) void step_all_k(
    const float* __restrict__ x, const float* __restrict__ w1,
    const float* __restrict__ wT3, const uint32_t* __restrict__ kb,
    uint32_t* __restrict__ sp2g) {
  __shared__ __align__(16) float  xhs_l[784];          // x/2 (signed)
  __shared__ __align__(16) float  pois_l[32 * 34];     // padded, zero halo
  __shared__ __align__(16) float  sp1_l[20 * 18 * 20]; // padded, zero halo
  __shared__ int8_t s2_l[50 * 196];                    // conv2 spikes
  __shared__ __align__(16) float  m2_l[50 * 196];      // conv2 membranes
  __shared__ float  m2s_l[2450];                       // pool2 membranes
  __shared__ float  m1s_l[20 * 196];                   // pool1 membranes
  __shared__ float  m1stash[512 * 21];                 // conv1 mem tt=2,3

  const int b  = blockIdx.x;
  const int t  = threadIdx.x;
  // P1 mapping
  const int lq = t & 255;
  const int ohu = __builtin_amdgcn_readfirstlane(t >> 8);
  const bool act1 = lq < 196;
  const int qy = lq / 14, qx = lq % 14;
  // P2 mapping: thread = (oc, row-pair)
  const bool act2 = t < 350;
  const int oc2 = t / 7;              // 0..49
  const int rp  = t % 7;              // 0..6
  const int y0  = 2 * rp;

  for (int p = t; p < 784; p += 512) {
    xhs_l[p] = x[b * 784 + p] * 0.5f;
  }
  // zero padded buffers (halos stay zero forever; data cells rewritten
  // every step before being read)
  for (int i = t; i < 32 * 34; i += 512) pois_l[i] = 0.f;
  for (int i = t; i < 20 * 360; i += 512) sp1_l[i] = 0.f;
  for (int i = t; i < 50 * 196; i += 512) m2_l[i] = 0.f;
  for (int i = t; i < 2450; i += 512) m2s_l[i] = 0.f;
  for (int i = t; i < 20 * 196; i += 512) m1s_l[i] = 0.f;
  for (int i = t; i < 512 * 21; i += 512) m1stash[i] = 0.f;

  // persistent register membranes: conv1 tt=0,1 only (tt=2,3 in m1stash)
  float m1p[2][10];
#pragma unroll
  for (int i = 0; i < 10; ++i) {
    m1p[0][i] = 0.f;
    m1p[1][i] = 0.f;
  }
  __syncthreads();

  // poisson for step 0
  {
    uint32_t k0 = kb[0], k1 = kb[1];
    for (int p = t; p < 784; p += 512) {
      uint32_t o0, o1;
      tf2x32(k0, k1, 0u, (uint32_t)(b * 784 + p), o0, o1);
      float r = __uint_as_float(((o0 ^ o1) >> 9) | 0x3F800000u) - 1.0f;
      float v = xhs_l[p];
      pois_l[(p / 28 + 2) * 34 + (p % 28 + 2)] =
          (fabsf(v) > r) ? ((v > 0.f) ? 1.f : -1.f) : 0.f;
    }
  }
  __syncthreads();

#define LDROW(rr, d) {                                                      \
    const float2* _pr = reinterpret_cast<const float2*>(                    \
        &pois_l[(2 * qy + (rr)) * 34 + 2 * qx]);                            \
    float2 _a0 = _pr[0], _a1 = _pr[1], _a2 = _pr[2];                        \
    d[0] = _a0.x; d[1] = _a0.y; d[2] = _a1.x;                               \
    d[3] = _a1.y; d[4] = _a2.x; d[5] = _a2.y; }

#define LD4(base, p0, p1, p2, p3) {                                         \
    const float4* _rn = reinterpret_cast<const float4*>(base);              \
    p0 = _rn[0]; p1 = _rn[1]; p2 = _rn[2]; p3 = _rn[3]; }

  for (int s = 0; s < STEPS; ++s) {
    // ---- P1: conv1 (10 oc of this half) + fire + pool1 + fire ----
    if (act1) {
      float rA[6], rB[6];
      LDROW(0, rA)
      LDROW(1, rB)
      float acc[4][10];
#pragma unroll
      for (int tt = 0; tt < 4; ++tt)
#pragma unroll
        for (int i = 0; i < 10; ++i) acc[tt][i] = 0.f;
#pragma unroll
      for (int ky = 0; ky < 5; ++ky) {
        // rA = padded row 2qy+ky (rows for tt 0,1), rB = row 2qy+ky+1
#pragma unroll
        for (int kx = 0; kx < 5; ++kx) {
#pragma unroll
          for (int i = 0; i < 10; ++i) {
            float w = w1[(ohu * 10 + i) * 25 + ky * 5 + kx];
            acc[0][i] += w * rA[kx];
            acc[1][i] += w * rA[kx + 1];
            acc[2][i] += w * rB[kx];
            acc[3][i] += w * rB[kx + 1];
          }
        }
        if (ky < 4) {
#pragma unroll
          for (int j = 0; j < 6; ++j) rA[j] = rB[j];
          LDROW(ky + 2, rB)
        }
      }
#pragma unroll
      for (int i = 0; i < 10; ++i) {
        float s4[4];
        // tt = 0,1: register membranes
#pragma unroll
        for (int tt = 0; tt < 2; ++tt) {
          float m = m1p[tt][i] + acc[tt][i];
          float sp = 0.f;
          if (m > 1.0f) { sp = 1.f; m = 0.f; }
          m1p[tt][i] = m;
          s4[tt] = sp;
        }
        // tt = 2,3: LDS-stashed membranes (controlled spill; each thread
        // exclusively owns its 21-float slab -> no races, no barrier dep)
        {
          float m = m1stash[t * 21 + i] + acc[2][i];
          float sp = 0.f;
          if (m > 1.0f) { sp = 1.f; m = 0.f; }
          m1stash[t * 21 + i] = m;
          s4[2] = sp;
        }
        {
          float m = m1stash[t * 21 + 10 + i] + acc[3][i];
          float sp = 0.f;
          if (m > 1.0f) { sp = 1.f; m = 0.f; }
          m1stash[t * 21 + 10 + i] = m;
          s4[3] = sp;
        }
        float a = 0.25f * (((s4[0] + s4[1]) + s4[2]) + s4[3]);
        int mi = (ohu * 10 + i) * 196 + lq;
        float mm = m1s_l[mi] + a;
        float spp = 0.f;
        if (mm > 0.75f) { spp = 1.f; mm = 0.f; }
        m1s_l[mi] = mm;
        sp1_l[(ohu * 10 + i) * 360 + (qy + 2) * 20 + (qx + 2)] = spp;
      }
    }
    __syncthreads();

    // ---- P2: conv2, packed-fp32 A/B row+weight pipeline ----
    if (act2) {
      f2 acc2[14];
#pragma unroll
      for (int xx = 0; xx < 14; ++xx) acc2[xx] = f2{0.f, 0.f};
      const float* wb = wT3 + oc2 * 1440;
#pragma unroll 1
      for (int ic = 0; ic < 20; ++ic) {
        const float* wic = wb + ic * 72;
        const float* spi = sp1_l + ic * 360;
        float4 a0, a1, a2, a3, b0, b1, b2, b3;
        f2 wpA[5], wpB[5];
        LD4(spi + (y0 + 0) * 20, a0, a1, a2, a3)
        ldwp(wic, 0, wpA);
        LD4(spi + (y0 + 1) * 20, b0, b1, b2, b3)
        ldwp(wic, 1, wpB);
        p2blk(a0, a1, a2, a3, wpA, acc2);
        LD4(spi + (y0 + 2) * 20, a0, a1, a2, a3)
        ldwp(wic, 2, wpA);
        __builtin_amdgcn_sched_barrier(0);
        p2blk(b0, b1, b2, b3, wpB, acc2);
        LD4(spi + (y0 + 3) * 20, b0, b1, b2, b3)
        ldwp(wic, 3, wpB);
        __builtin_amdgcn_sched_barrier(0);
        p2blk(a0, a1, a2, a3, wpA, acc2);
        LD4(spi + (y0 + 4) * 20, a0, a1, a2, a3)
        ldwp(wic, 4, wpA);
        __builtin_amdgcn_sched_barrier(0);
        p2blk(b0, b1, b2, b3, wpB, acc2);
        LD4(spi + (y0 + 5) * 20, b0, b1, b2, b3)
        ldwp(wic, 5, wpB);
        __builtin_amdgcn_sched_barrier(0);
        p2blk(a0, a1, a2, a3, wpA, acc2);
        p2blk(b0, b1, b2, b3, wpB, acc2);
      }
      // fire: r=0 uses .x, r=1 uses .y — same order as scalar version
#pragma unroll
      for (int xx = 0; xx < 14; ++xx) {
        int li = oc2 * 196 + y0 * 14 + xx;
        float m = m2_l[li] + acc2[xx].x;
        int8_t sp = 0;
        if (m > 1.0f) { sp = 1; m = 0.f; }
        m2_l[li] = m;
        s2_l[li] = sp;
      }
#pragma unroll
      for (int xx = 0; xx < 14; ++xx) {
        int li = oc2 * 196 + (y0 + 1) * 14 + xx;
        float m = m2_l[li] + acc2[xx].y;
        int8_t sp = 0;
        if (m > 1.0f) { sp = 1; m = 0.f; }
        m2_l[li] = m;
        s2_l[li] = sp;
      }
    }
    __syncthreads();

    // ---- P3: pool2 + fire -> ballot pack, + poisson(s+1) ----
#pragma unroll
    for (int i = 0; i < 5; ++i) {
      int e = i * 512 + t;
      bool fire = false;
      if (e < 2450) {
        int oc = e / 49, qq = e % 49;
        int yo = qq / 7, xo = qq % 7;
        int ib = oc * 196 + 2 * yo * 14 + 2 * xo;
        float s00 = (float)s2_l[ib];
        float s01 = (float)s2_l[ib + 1];
        float s10 = (float)s2_l[ib + 14];
        float s11 = (float)s2_l[ib + 15];
        float a = 0.25f * (((s00 + s01) + s10) + s11);
        float m = m2s_l[e] + a;
        if (m > 0.75f) { fire = true; m = 0.f; }
        m2s_l[e] = m;
      }
      unsigned long long mask = __ballot(fire);
      int base = (e & ~63);
      if ((t & 63) == 0 && base < 2450) {
        int d = base >> 5;
        sp2g[b * 7700 + s * 77 + d] = (uint32_t)mask;
        if (base + 32 < 2450)
          sp2g[b * 7700 + s * 77 + d + 1] = (uint32_t)(mask >> 32);
      }
    }
    if (s + 1 < STEPS) {
      uint32_t k0 = kb[2 * (s + 1)], k1 = kb[2 * (s + 1) + 1];
      for (int p = t; p < 784; p += 512) {
        uint32_t o0, o1;
        tf2x32(k0, k1, 0u, (uint32_t)(b * 784 + p), o0, o1);
        float r = __uint_as_float(((o0 ^ o1) >> 9) | 0x3F800000u) - 1.0f;
        float v = xhs_l[p];
        pois_l[(p / 28 + 2) * 34 + (p % 28 + 2)] =
            (fabsf(v) > r) ? ((v > 0.f) ? 1.f : -1.f) : 0.f;
      }
    }
    __syncthreads();
  }
#undef LDROW
#undef LD4
}

// ---------------------------------------------------------------------------
// fc0 (R14-proven): block = sample, lane = neuron; wave-uniform ctz over
// spike bits; acc += wf0T[k][n] coalesced; k ascending -> bit-identical.
// ---------------------------------------------------------------------------
__global__ __launch_bounds__(256) void fc0f_k(
    const uint32_t* __restrict__ sp2g, const float* __restrict__ wf0T,
    float* __restrict__ Tf0g) {
  __shared__ uint32_t mk[77];
  const int b = blockIdx.x;
  const int n = threadIdx.x;
  float m = 0.f, T = 0.f;
  for (int s = 0; s < STEPS; ++s) {
    __syncthreads();
    if (n < 77) mk[n] = sp2g[b * 7700 + s * 77 + n];
    __syncthreads();
    float acc = 0.f;
    for (int d = 0; d < 77; ++d) {
      uint32_t um = mk[d];
      while (um) {
        int j = __builtin_ctz(um);
        um &= um - 1;
        acc += wf0T[((d << 5) + j) * 256 + n];
      }
    }
    m += acc;
    if (m > 1.0f) { T += 1.f; m = 0.f; }
  }
  if (n < 200) Tf0g[b * 200 + n] = T;
}

// ---------------------------------------------------------------------------
// final: out[b][i] = (Tf0[b][:] . wf1[i][:]) / 1 / 100   (j ascending)
// ---------------------------------------------------------------------------
__global__ void fc1_k(const float* __restrict__ Tf0,
                      const float* __restrict__ wf1,
                      float* __restrict__ out) {
  int idx = blockIdx.x * blockDim.x + threadIdx.x;
  if (idx >= 5120) return;
  int b = idx / 10, i = idx % 10;
  float a = 0.f;
  for (int j = 0; j < 200; ++j) a += Tf0[b * 200 + j] * wf1[i * 200 + j];
  out[idx] = (a / 1.0f) / 100.0f;
}

// ---------------------------------------------------------------------------
extern "C" void kernel_launch(void* const* d_in, const int* in_sizes, int n_in,
                              void* d_out, int out_size, void* d_ws, size_t ws_size,
                              hipStream_t stream) {
  (void)in_sizes; (void)n_in; (void)out_size; (void)ws_size;
  const float* x   = (const float*)d_in[0];
  const float* w1  = (const float*)d_in[1];
  const float* w2  = (const float*)d_in[2];
  const float* wf0 = (const float*)d_in[3];
  const float* wf1 = (const float*)d_in[4];
  float* out = (float*)d_out;
  char* ws = (char*)d_ws;

  // workspace: Tf0 | wT3 | keys | wf0T | sp2 bitmask  (~19 MB)
  const size_t tf0_b  = 512ull * 200 * 4;
  const size_t wt_b   = 50ull * 20 * 72 * 4;  // 288000 B
  const size_t key_b  = 1024;
  const size_t wf0t_b = 2450ull * 256 * 4;
  float*    Tf0g = (float*)ws;
  float*    wT3  = (float*)(ws + tf0_b);
  uint32_t* kb   = (uint32_t*)(ws + tf0_b + wt_b);
  float*    wf0T = (float*)(ws + tf0_b + wt_b + key_b);
  uint32_t* sp2g = (uint32_t*)(ws + tf0_b + wt_b + key_b + wf0t_b);

  keys_k<<<1, 128, 0, stream>>>(kb);
  wt3_k<<<282, 256, 0, stream>>>(w2, wT3);
  wf0t_k<<<2450, 256, 0, stream>>>(wf0, wf0T);
  step_all_k<<<512, 512, 0, stream>>>(x, w1, wT3, kb, sp2g);
  fc0f_k<<<512, 256, 0, stream>>>(sp2g, wf0T, Tf0g);
  fc1_k<<<20, 256, 0, stream>>>(Tf0g, wf1, out);
}

// Round 10
// 9911.726 us; speedup vs baseline: 1.1708x; 1.0468x over previous
//
#include <hip/hip_runtime.h>
#include <stdint.h>

#define STEPS 100

typedef float f2 __attribute__((ext_vector_type(2)));

// ---------------------------------------------------------------------------
// Threefry2x32 (JAX-exact, 20 rounds)
// ---------------------------------------------------------------------------
__device__ __forceinline__ uint32_t rotl32(uint32_t v, int r) {
  return (v << r) | (v >> (32 - r));
}

__device__ __forceinline__ void tf2x32(uint32_t k0, uint32_t k1,
                                       uint32_t x0, uint32_t x1,
                                       uint32_t& o0, uint32_t& o1) {
  uint32_t ks2 = k0 ^ k1 ^ 0x1BD11BDAu;
  x0 += k0; x1 += k1;
#define RND(r) { x0 += x1; x1 = rotl32(x1, (r)); x1 ^= x0; }
  RND(13) RND(15) RND(26) RND(6)
  x0 += k1;  x1 += ks2 + 1u;
  RND(17) RND(29) RND(16) RND(24)
  x0 += ks2; x1 += k0 + 2u;
  RND(13) RND(15) RND(26) RND(6)
  x0 += k0;  x1 += k1 + 3u;
  RND(17) RND(29) RND(16) RND(24)
  x0 += k1;  x1 += ks2 + 4u;
  RND(13) RND(15) RND(26) RND(6)
  x0 += ks2; x1 += k0 + 5u;
#undef RND
  o0 = x0; o1 = x1;
}

__global__ void keys_k(uint32_t* __restrict__ kb) {
  int i = threadIdx.x;
  if (i < STEPS) {
    uint32_t a, b;
    tf2x32(0u, 42u, 0u, (uint32_t)i, a, b);
    kb[2 * i] = a;
    kb[2 * i + 1] = b;
  }
}

// wT3: row-PAIRED weights for v_pk_fma_f32.
// Layout [oc][ic][jr][12]: jr slot = 5 float2 pairs (10 floats) + 2 pad.
// pair[kx] = (lo = w[jr][kx] if jr<5 else 0,  hi = w[jr-1][kx] if jr>=1
// else 0). Slot stride 48B -> every jr slot 16B-aligned.
__global__ void wt3_k(const float* __restrict__ w2, float* __restrict__ wT3) {
  int i = blockIdx.x * blockDim.x + threadIdx.x;
  if (i >= 50 * 20 * 72) return;
  int oc = i / 1440, r = i % 1440;
  int ic = r / 72, q = r % 72;
  int jr = q / 12, p = q % 12;
  float v = 0.f;
  if (p < 10) {
    int kx = p >> 1, h = p & 1;
    if (h == 0 && jr < 5)  v = w2[oc * 500 + ic * 25 + jr * 5 + kx];
    if (h == 1 && jr >= 1) v = w2[oc * 500 + ic * 25 + (jr - 1) * 5 + kx];
  }
  wT3[i] = v;
}

// wf0 transpose, padded: wf0T[k*256 + n] = (n<200) ? wf0[n*2450+k] : 0
__global__ void wf0t_k(const float* __restrict__ wf0,
                       float* __restrict__ wf0T) {
  int i = blockIdx.x * blockDim.x + threadIdx.x;
  if (i >= 2450 * 256) return;
  int k = i >> 8, n = i & 255;
  wf0T[i] = (n < 200) ? wf0[n * 2450 + k] : 0.f;
}

// ---------------------------------------------------------------------------
// P2 packed-FMA block (v17-proven): both output rows advance together via
// v_pk_fma_f32. Edge half-pairs and the u[16],u[17] zeros are exact no-ops
// (acc built from +0 by adds is never -0). Bit-identical to scalar chain.
// ---------------------------------------------------------------------------
__device__ __forceinline__ void p2blk(const float4& q0, const float4& q1,
                                      const float4& q2, const float4& q3,
                                      const f2* wp, f2* acc2) {
  float u[18] = {q0.x, q0.y, q0.z, q0.w, q1.x, q1.y, q1.z, q1.w,
                 q2.x, q2.y, q2.z, q2.w, q3.x, q3.y, q3.z, q3.w, 0.f, 0.f};
#pragma unroll
  for (int kx = 0; kx < 5; ++kx) {
    f2 w = wp[kx];
#pragma unroll
    for (int xx = 0; xx < 14; ++xx) {
      f2 us = {u[xx + kx], u[xx + kx]};
      acc2[xx] = __builtin_elementwise_fma(w, us, acc2[xx]);
    }
  }
}

__device__ __forceinline__ void ldwp(const float* wic, int jr, f2* wp) {
  const float4* p = reinterpret_cast<const float4*>(wic + jr * 12);
  float4 a = p[0], b = p[1];
  wp[0] = f2{a.x, a.y}; wp[1] = f2{a.z, a.w};
  wp[2] = f2{b.x, b.y}; wp[3] = f2{b.z, b.w};
  float2 c = *reinterpret_cast<const float2*>(wic + jr * 12 + 8);
  wp[4] = f2{c.x, c.y};
}

// ---------------------------------------------------------------------------
// PERSISTENT per-sample kernel v18: stall removal + P3 fusion.
// v17 counters: VGPR 88 (pk emitted), WRITE at 15.4 MB no-spill baseline,
// but wall 120K cyc/step vs ~46K busiest-SIMD issue -> latency-bound.
// Exposure: ldwp (global L2 ~250cy) consumed 1 segment (~140cy) later, and
// each ic's first 2 segments consume loads issued immediately before.
//  * P2: rows 2-buffer (LDS, dist 2 = covered) + weights 3-buffer W0/W1/W2
//    with every ldwp issued 2-3 segments ahead ACROSS ic boundaries
//    (prologue + icn clamp) -> steady state never waits on weights.
//  * pool2 FUSED into P2: the 2x2 pool window of (oc, yo=rp) is exactly
//    this thread's row-pair -> pool from in-reg fire bits, owner-exclusive
//    m2s chain, 7-bit byte to fb[t]. s2_l + the whole P3 phase deleted;
//    77-thread word assembly reproduces the exact sp2g bit layout.
//    2 barriers/step instead of 3 (assembly -> next-P1 is program order).
//  * poisson(s+1) under P2's shadow on idle waves 6-7 (t>=384).
// All FMA/fire/pool chains + word layout unchanged -> bit-identical.
// LDS: 3136+4352+28800+39200+9800+15680+43008+352 = 144328 B.
// ---------------------------------------------------------------------------
__global__ __launch_bounds__(512, 2) void step_all_k(
    const float* __restrict__ x, const float* __restrict__ w1,
    const float* __restrict__ wT3, const uint32_t* __restrict__ kb,
    uint32_t* __restrict__ sp2g) {
  __shared__ __align__(16) float  xhs_l[784];          // x/2 (signed)
  __shared__ __align__(16) float  pois_l[32 * 34];     // padded, zero halo
  __shared__ __align__(16) float  sp1_l[20 * 18 * 20]; // padded, zero halo
  __shared__ __align__(16) float  m2_l[50 * 196];      // conv2 membranes
  __shared__ float    m2s_l[2450];                     // pool2 membranes
  __shared__ float    m1s_l[20 * 196];                 // pool1 membranes
  __shared__ float    m1stash[512 * 21];               // conv1 mem tt=2,3
  __shared__ uint8_t  fb[352];                         // pool2 fire bytes

  const int b  = blockIdx.x;
  const int t  = threadIdx.x;
  // P1 mapping
  const int lq = t & 255;
  const int ohu = __builtin_amdgcn_readfirstlane(t >> 8);
  const bool act1 = lq < 196;
  const int qy = lq / 14, qx = lq % 14;
  // P2 mapping: thread = (oc, row-pair)
  const bool act2 = t < 350;
  const int oc2 = t / 7;              // 0..49
  const int rp  = t % 7;              // 0..6
  const int y0  = 2 * rp;

  for (int p = t; p < 784; p += 512) {
    xhs_l[p] = x[b * 784 + p] * 0.5f;
  }
  // zero padded buffers (halos stay zero forever; data cells rewritten
  // every step before being read)
  for (int i = t; i < 32 * 34; i += 512) pois_l[i] = 0.f;
  for (int i = t; i < 20 * 360; i += 512) sp1_l[i] = 0.f;
  for (int i = t; i < 50 * 196; i += 512) m2_l[i] = 0.f;
  for (int i = t; i < 2450; i += 512) m2s_l[i] = 0.f;
  for (int i = t; i < 20 * 196; i += 512) m1s_l[i] = 0.f;
  for (int i = t; i < 512 * 21; i += 512) m1stash[i] = 0.f;
  if (t < 352) fb[t] = 0;

  // persistent register membranes: conv1 tt=0,1 only (tt=2,3 in m1stash)
  float m1p[2][10];
#pragma unroll
  for (int i = 0; i < 10; ++i) {
    m1p[0][i] = 0.f;
    m1p[1][i] = 0.f;
  }
  __syncthreads();

  // poisson for step 0 (all threads)
  {
    uint32_t k0 = kb[0], k1 = kb[1];
    for (int p = t; p < 784; p += 512) {
      uint32_t o0, o1;
      tf2x32(k0, k1, 0u, (uint32_t)(b * 784 + p), o0, o1);
      float r = __uint_as_float(((o0 ^ o1) >> 9) | 0x3F800000u) - 1.0f;
      float v = xhs_l[p];
      pois_l[(p / 28 + 2) * 34 + (p % 28 + 2)] =
          (fabsf(v) > r) ? ((v > 0.f) ? 1.f : -1.f) : 0.f;
    }
  }
  __syncthreads();

#define LDROW(rr, d) {                                                      \
    const float2* _pr = reinterpret_cast<const float2*>(                    \
        &pois_l[(2 * qy + (rr)) * 34 + 2 * qx]);                            \
    float2 _a0 = _pr[0], _a1 = _pr[1], _a2 = _pr[2];                        \
    d[0] = _a0.x; d[1] = _a0.y; d[2] = _a1.x;                               \
    d[3] = _a1.y; d[4] = _a2.x; d[5] = _a2.y; }

#define LD4(icv, jrv, p0, p1, p2, p3) {                                     \
    const float4* _rn = reinterpret_cast<const float4*>(                    \
        sp1_l + (icv) * 360 + (y0 + (jrv)) * 20);                           \
    p0 = _rn[0]; p1 = _rn[1]; p2 = _rn[2]; p3 = _rn[3]; }

  for (int s = 0; s < STEPS; ++s) {
    // ---- P1: conv1 (10 oc of this half) + fire + pool1 + fire ----
    if (act1) {
      float rA[6], rB[6];
      LDROW(0, rA)
      LDROW(1, rB)
      float acc[4][10];
#pragma unroll
      for (int tt = 0; tt < 4; ++tt)
#pragma unroll
        for (int i = 0; i < 10; ++i) acc[tt][i] = 0.f;
#pragma unroll
      for (int ky = 0; ky < 5; ++ky) {
        // rA = padded row 2qy+ky (rows for tt 0,1), rB = row 2qy+ky+1
#pragma unroll
        for (int kx = 0; kx < 5; ++kx) {
#pragma unroll
          for (int i = 0; i < 10; ++i) {
            float w = w1[(ohu * 10 + i) * 25 + ky * 5 + kx];
            acc[0][i] += w * rA[kx];
            acc[1][i] += w * rA[kx + 1];
            acc[2][i] += w * rB[kx];
            acc[3][i] += w * rB[kx + 1];
          }
        }
        if (ky < 4) {
#pragma unroll
          for (int j = 0; j < 6; ++j) rA[j] = rB[j];
          LDROW(ky + 2, rB)
        }
      }
#pragma unroll
      for (int i = 0; i < 10; ++i) {
        float s4[4];
        // tt = 0,1: register membranes
#pragma unroll
        for (int tt = 0; tt < 2; ++tt) {
          float m = m1p[tt][i] + acc[tt][i];
          float sp = 0.f;
          if (m > 1.0f) { sp = 1.f; m = 0.f; }
          m1p[tt][i] = m;
          s4[tt] = sp;
        }
        // tt = 2,3: LDS-stashed membranes (thread-exclusive slab)
        {
          float m = m1stash[t * 21 + i] + acc[2][i];
          float sp = 0.f;
          if (m > 1.0f) { sp = 1.f; m = 0.f; }
          m1stash[t * 21 + i] = m;
          s4[2] = sp;
        }
        {
          float m = m1stash[t * 21 + 10 + i] + acc[3][i];
          float sp = 0.f;
          if (m > 1.0f) { sp = 1.f; m = 0.f; }
          m1stash[t * 21 + 10 + i] = m;
          s4[3] = sp;
        }
        float a = 0.25f * (((s4[0] + s4[1]) + s4[2]) + s4[3]);
        int mi = (ohu * 10 + i) * 196 + lq;
        float mm = m1s_l[mi] + a;
        float spp = 0.f;
        if (mm > 0.75f) { spp = 1.f; mm = 0.f; }
        m1s_l[mi] = mm;
        sp1_l[(ohu * 10 + i) * 360 + (qy + 2) * 20 + (qx + 2)] = spp;
      }
    }
    __syncthreads();

    // ---- P2: conv2 deep pipeline + fused pool2; poisson on waves 6,7 ----
    if (act2) {
      f2 acc2[14];
#pragma unroll
      for (int xx = 0; xx < 14; ++xx) acc2[xx] = f2{0.f, 0.f};
      const float* wb = wT3 + oc2 * 1440;
      float4 A0, A1, A2, A3, B0, B1, B2, B3;
      f2 W0[5], W1[5], W2[5];
      // prologue: rows jr0->A, jr1->B; weights jr0->W0, jr1->W1, jr2->W2
      LD4(0, 0, A0, A1, A2, A3)
      ldwp(wb, 0, W0);
      LD4(0, 1, B0, B1, B2, B3)
      ldwp(wb, 1, W1);
      ldwp(wb, 2, W2);
#pragma unroll 1
      for (int ic = 0; ic < 20; ++ic) {
        const int icn = (ic < 19) ? ic + 1 : 19;
        const float* wic  = wb + ic * 72;
        const float* wicn = wb + icn * 72;
        p2blk(A0, A1, A2, A3, W0, acc2);             // jr0
        LD4(ic, 2, A0, A1, A2, A3)
        ldwp(wic, 3, W0);
        __builtin_amdgcn_sched_barrier(0);
        p2blk(B0, B1, B2, B3, W1, acc2);             // jr1
        LD4(ic, 3, B0, B1, B2, B3)
        ldwp(wic, 4, W1);
        __builtin_amdgcn_sched_barrier(0);
        p2blk(A0, A1, A2, A3, W2, acc2);             // jr2
        LD4(ic, 4, A0, A1, A2, A3)
        ldwp(wic, 5, W2);
        __builtin_amdgcn_sched_barrier(0);
        p2blk(B0, B1, B2, B3, W0, acc2);             // jr3
        LD4(ic, 5, B0, B1, B2, B3)
        ldwp(wicn, 0, W0);
        __builtin_amdgcn_sched_barrier(0);
        p2blk(A0, A1, A2, A3, W1, acc2);             // jr4
        LD4(icn, 0, A0, A1, A2, A3)
        ldwp(wicn, 1, W1);
        __builtin_amdgcn_sched_barrier(0);
        p2blk(B0, B1, B2, B3, W2, acc2);             // jr5
        LD4(icn, 1, B0, B1, B2, B3)
        ldwp(wicn, 2, W2);
        __builtin_amdgcn_sched_barrier(0);
      }
      // fire (row y0 then y0+1, xx asc — same order as before)
      float f0[14], f1[14];
#pragma unroll
      for (int xx = 0; xx < 14; ++xx) {
        int li = oc2 * 196 + y0 * 14 + xx;
        float m = m2_l[li] + acc2[xx].x;
        float sp = 0.f;
        if (m > 1.0f) { sp = 1.f; m = 0.f; }
        m2_l[li] = m;
        f0[xx] = sp;
      }
#pragma unroll
      for (int xx = 0; xx < 14; ++xx) {
        int li = oc2 * 196 + (y0 + 1) * 14 + xx;
        float m = m2_l[li] + acc2[xx].y;
        float sp = 0.f;
        if (m > 1.0f) { sp = 1.f; m = 0.f; }
        m2_l[li] = m;
        f1[xx] = sp;
      }
      // fused pool2 + fire (this thread owns pool row yo=rp of oc2)
      uint32_t byte = 0;
#pragma unroll
      for (int xo = 0; xo < 7; ++xo) {
        float a = 0.25f * (((f0[2 * xo] + f0[2 * xo + 1]) + f1[2 * xo]) +
                           f1[2 * xo + 1]);
        int e = oc2 * 49 + rp * 7 + xo;
        float m = m2s_l[e] + a;
        uint32_t bit = 0;
        if (m > 0.75f) { bit = 1; m = 0.f; }
        m2s_l[e] = m;
        byte |= bit << xo;
      }
      fb[t] = (uint8_t)byte;
    } else if (t >= 384) {
      // poisson for step s+1 under P2's shadow (waves 6,7 idle in P2)
      if (s + 1 < STEPS) {
        uint32_t k0 = kb[2 * (s + 1)], k1 = kb[2 * (s + 1) + 1];
        for (int p = t - 384; p < 784; p += 128) {
          uint32_t o0, o1;
          tf2x32(k0, k1, 0u, (uint32_t)(b * 784 + p), o0, o1);
          float r = __uint_as_float(((o0 ^ o1) >> 9) | 0x3F800000u) - 1.0f;
          float v = xhs_l[p];
          pois_l[(p / 28 + 2) * 34 + (p % 28 + 2)] =
              (fabsf(v) > r) ? ((v > 0.f) ? 1.f : -1.f) : 0.f;
        }
      }
    }
    __syncthreads();

    // ---- word assembly: bit e of sp2 stream = fb[e/7] bit (e%7) ----
    if (t < 77) {
      int j0 = (32 * t) / 7;
      uint64_t accw = 0;
#pragma unroll
      for (int jj = 0; jj < 6; ++jj) {
        int j = j0 + jj;
        uint32_t bv = (j < 350) ? (uint32_t)fb[j] : 0u;
        accw |= (uint64_t)bv << (7 * j - 32 * t + 6);
      }
      sp2g[b * 7700 + s * 77 + t] = (uint32_t)(accw >> 6);
    }
    // no barrier: next-step P1 writes don't conflict with assembly reads
  }
#undef LDROW
#undef LD4
}

// ---------------------------------------------------------------------------
// fc0 (R14-proven): block = sample, lane = neuron; wave-uniform ctz over
// spike bits; acc += wf0T[k][n] coalesced; k ascending -> bit-identical.
// ---------------------------------------------------------------------------
__global__ __launch_bounds__(256) void fc0f_k(
    const uint32_t* __restrict__ sp2g, const float* __restrict__ wf0T,
    float* __restrict__ Tf0g) {
  __shared__ uint32_t mk[77];
  const int b = blockIdx.x;
  const int n = threadIdx.x;
  float m = 0.f, T = 0.f;
  for (int s = 0; s < STEPS; ++s) {
    __syncthreads();
    if (n < 77) mk[n] = sp2g[b * 7700 + s * 77 + n];
    __syncthreads();
    float acc = 0.f;
    for (int d = 0; d < 77; ++d) {
      uint32_t um = mk[d];
      while (um) {
        int j = __builtin_ctz(um);
        um &= um - 1;
        acc += wf0T[((d << 5) + j) * 256 + n];
      }
    }
    m += acc;
    if (m > 1.0f) { T += 1.f; m = 0.f; }
  }
  if (n < 200) Tf0g[b * 200 + n] = T;
}

// ---------------------------------------------------------------------------
// final: out[b][i] = (Tf0[b][:] . wf1[i][:]) / 1 / 100   (j ascending)
// ---------------------------------------------------------------------------
__global__ void fc1_k(const float* __restrict__ Tf0,
                      const float* __restrict__ wf1,
                      float* __restrict__ out) {
  int idx = blockIdx.x * blockDim.x + threadIdx.x;
  if (idx >= 5120) return;
  int b = idx / 10, i = idx % 10;
  float a = 0.f;
  for (int j = 0; j < 200; ++j) a += Tf0[b * 200 + j] * wf1[i * 200 + j];
  out[idx] = (a / 1.0f) / 100.0f;
}

// ---------------------------------------------------------------------------
extern "C" void kernel_launch(void* const* d_in, const int* in_sizes, int n_in,
                              void* d_out, int out_size, void* d_ws, size_t ws_size,
                              hipStream_t stream) {
  (void)in_sizes; (void)n_in; (void)out_size; (void)ws_size;
  const float* x   = (const float*)d_in[0];
  const float* w1  = (const float*)d_in[1];
  const float* w2  = (const float*)d_in[2];
  const float* wf0 = (const float*)d_in[3];
  const float* wf1 = (const float*)d_in[4];
  float* out = (float*)d_out;
  char* ws = (char*)d_ws;

  // workspace: Tf0 | wT3 | keys | wf0T | sp2 bitmask  (~19 MB)
  const size_t tf0_b  = 512ull * 200 * 4;
  const size_t wt_b   = 50ull * 20 * 72 * 4;  // 288000 B
  const size_t key_b  = 1024;
  const size_t wf0t_b = 2450ull * 256 * 4;
  float*    Tf0g = (float*)ws;
  float*    wT3  = (float*)(ws + tf0_b);
  uint32_t* kb   = (uint32_t*)(ws + tf0_b + wt_b);
  float*    wf0T = (float*)(ws + tf0_b + wt_b + key_b);
  uint32_t* sp2g = (uint32_t*)(ws + tf0_b + wt_b + key_b + wf0t_b);

  keys_k<<<1, 128, 0, stream>>>(kb);
  wt3_k<<<282, 256, 0, stream>>>(w2, wT3);
  wf0t_k<<<2450, 256, 0, stream>>>(wf0, wf0T);
  step_all_k<<<512, 512, 0, stream>>>(x, w1, wT3, kb, sp2g);
  fc0f_k<<<512, 256, 0, stream>>>(sp2g, wf0T, Tf0g);
  fc1_k<<<20, 256, 0, stream>>>(Tf0g, wf1, out);
}

// Round 11
// 9838.599 us; speedup vs baseline: 1.1795x; 1.0074x over previous
//
#include <hip/hip_runtime.h>
#include <stdint.h>

#define STEPS 100

typedef float f2 __attribute__((ext_vector_type(2)));

// ---------------------------------------------------------------------------
// Threefry2x32 (JAX-exact, 20 rounds)
// ---------------------------------------------------------------------------
__device__ __forceinline__ uint32_t rotl32(uint32_t v, int r) {
  return (v << r) | (v >> (32 - r));
}

__device__ __forceinline__ void tf2x32(uint32_t k0, uint32_t k1,
                                       uint32_t x0, uint32_t x1,
                                       uint32_t& o0, uint32_t& o1) {
  uint32_t ks2 = k0 ^ k1 ^ 0x1BD11BDAu;
  x0 += k0; x1 += k1;
#define RND(r) { x0 += x1; x1 = rotl32(x1, (r)); x1 ^= x0; }
  RND(13) RND(15) RND(26) RND(6)
  x0 += k1;  x1 += ks2 + 1u;
  RND(17) RND(29) RND(16) RND(24)
  x0 += ks2; x1 += k0 + 2u;
  RND(13) RND(15) RND(26) RND(6)
  x0 += k0;  x1 += k1 + 3u;
  RND(17) RND(29) RND(16) RND(24)
  x0 += k1;  x1 += ks2 + 4u;
  RND(13) RND(15) RND(26) RND(6)
  x0 += ks2; x1 += k0 + 5u;
#undef RND
  o0 = x0; o1 = x1;
}

__global__ void keys_k(uint32_t* __restrict__ kb) {
  int i = threadIdx.x;
  if (i < STEPS) {
    uint32_t a, b;
    tf2x32(0u, 42u, 0u, (uint32_t)i, a, b);
    kb[2 * i] = a;
    kb[2 * i + 1] = b;
  }
}

// wT2 layout [oc][ic][28-pad]: wv loads = 7 aligned float4; the 7 rp-threads
// of one oc hit the same cachelines (broadcast).
__global__ void wt_k(const float* __restrict__ w2, float* __restrict__ wT2) {
  int i = blockIdx.x * blockDim.x + threadIdx.x;
  if (i >= 50 * 560) return;
  int oc = i / 560, r = i % 560;
  int ic = r / 28, j = r % 28;
  wT2[i] = (j < 25) ? w2[oc * 500 + ic * 25 + j] : 0.f;
}

// wf0 transpose, padded: wf0T[k*256 + n] = (n<200) ? wf0[n*2450+k] : 0
__global__ void wf0t_k(const float* __restrict__ wf0,
                       float* __restrict__ wf0T) {
  int i = blockIdx.x * blockDim.x + threadIdx.x;
  if (i >= 2450 * 256) return;
  int k = i >> 8, n = i & 255;
  wf0T[i] = (n < 200) ? wf0[n * 2450 + k] : 0.f;
}

// ---------------------------------------------------------------------------
// v19 P2 block: pack along OUTPUT-COLUMN pairs. a0/a1[j] = columns (2j,2j+1)
// of rows r0/r1. Weight = splat (loop-invariant, {w,w} same-reg foldable);
// even-kx u-pairs are the natural b128 register pairs; odd-kx needs 8 packs
// shared across both rows. Edge terms multiply exact +/-0 -> adding +/-0
// never changes acc -> per-output chain (kx asc within row, r0 before r1)
// is byte-identical to the scalar version.
// ---------------------------------------------------------------------------
template <int JR>
__device__ __forceinline__ void p2x(const float4& q0, const float4& q1,
                                    const float4& q2, const float4& q3,
                                    const float (&wv)[28],
                                    f2 (&a0)[7], f2 (&a1)[7]) {
  f2 E[8] = {{q0.x, q0.y}, {q0.z, q0.w}, {q1.x, q1.y}, {q1.z, q1.w},
             {q2.x, q2.y}, {q2.z, q2.w}, {q3.x, q3.y}, {q3.z, q3.w}};
  f2 O[8] = {{q0.y, q0.z}, {q0.w, q1.x}, {q1.y, q1.z}, {q1.w, q2.x},
             {q2.y, q2.z}, {q2.w, q3.x}, {q3.y, q3.z}, {q3.w, 0.f}};
  if (JR < 5) {                      // row r0, ky = JR
    f2 W;
    W = f2{wv[JR * 5 + 0], wv[JR * 5 + 0]};
#pragma unroll
    for (int j = 0; j < 7; ++j) a0[j] = __builtin_elementwise_fma(W, E[j], a0[j]);
    W = f2{wv[JR * 5 + 1], wv[JR * 5 + 1]};
#pragma unroll
    for (int j = 0; j < 7; ++j) a0[j] = __builtin_elementwise_fma(W, O[j], a0[j]);
    W = f2{wv[JR * 5 + 2], wv[JR * 5 + 2]};
#pragma unroll
    for (int j = 0; j < 7; ++j) a0[j] = __builtin_elementwise_fma(W, E[j + 1], a0[j]);
    W = f2{wv[JR * 5 + 3], wv[JR * 5 + 3]};
#pragma unroll
    for (int j = 0; j < 7; ++j) a0[j] = __builtin_elementwise_fma(W, O[j + 1], a0[j]);
    W = f2{wv[JR * 5 + 4], wv[JR * 5 + 4]};
#pragma unroll
    for (int j = 0; j < 6; ++j) a0[j] = __builtin_elementwise_fma(W, E[j + 2], a0[j]);
  }
  if (JR >= 1) {                     // row r1, ky = JR-1
    constexpr int K = (JR - 1) * 5;
    f2 W;
    W = f2{wv[K + 0], wv[K + 0]};
#pragma unroll
    for (int j = 0; j < 7; ++j) a1[j] = __builtin_elementwise_fma(W, E[j], a1[j]);
    W = f2{wv[K + 1], wv[K + 1]};
#pragma unroll
    for (int j = 0; j < 7; ++j) a1[j] = __builtin_elementwise_fma(W, O[j], a1[j]);
    W = f2{wv[K + 2], wv[K + 2]};
#pragma unroll
    for (int j = 0; j < 7; ++j) a1[j] = __builtin_elementwise_fma(W, E[j + 1], a1[j]);
    W = f2{wv[K + 3], wv[K + 3]};
#pragma unroll
    for (int j = 0; j < 7; ++j) a1[j] = __builtin_elementwise_fma(W, O[j + 1], a1[j]);
    W = f2{wv[K + 4], wv[K + 4]};
#pragma unroll
    for (int j = 0; j < 6; ++j) a1[j] = __builtin_elementwise_fma(W, E[j + 2], a1[j]);
  }
}

// ---------------------------------------------------------------------------
// PERSISTENT per-sample kernel v19: flip the pk packing axis.
// v18 audit: wall 116K cyc/step, VALU issue 72K/SIMD but countable work only
// ~42K -> ~30K unexplained == the per-FMA {u,u} splat movs of the row-pair
// packing (8040/wave; also explains v17's tiny -3.5%). Fix: pack along xx
// so the SPLAT operand is the weight (hoisted, 10/block) and u-pairs are
// natural b128 register pairs (even kx free, odd kx = 8 packs/block).
// ~86 issue/block vs ~134. Weights back to scalar wv[28] (wT2, 7 float4/ic,
// template<JR> static indexing). Rows/fences/pool-fusion/poisson frozen
// from v18. Per-output chains unchanged -> bit-identical output.
// ---------------------------------------------------------------------------
__global__ __launch_bounds__(512, 2) void step_all_k(
    const float* __restrict__ x, const float* __restrict__ w1,
    const float* __restrict__ wT2, const uint32_t* __restrict__ kb,
    uint32_t* __restrict__ sp2g) {
  __shared__ __align__(16) float  xhs_l[784];          // x/2 (signed)
  __shared__ __align__(16) float  pois_l[32 * 34];     // padded, zero halo
  __shared__ __align__(16) float  sp1_l[20 * 18 * 20]; // padded, zero halo
  __shared__ __align__(16) float  m2_l[50 * 196];      // conv2 membranes
  __shared__ float    m2s_l[2450];                     // pool2 membranes
  __shared__ float    m1s_l[20 * 196];                 // pool1 membranes
  __shared__ float    m1stash[512 * 21];               // conv1 mem tt=2,3
  __shared__ uint8_t  fb[352];                         // pool2 fire bytes

  const int b  = blockIdx.x;
  const int t  = threadIdx.x;
  // P1 mapping
  const int lq = t & 255;
  const int ohu = __builtin_amdgcn_readfirstlane(t >> 8);
  const bool act1 = lq < 196;
  const int qy = lq / 14, qx = lq % 14;
  // P2 mapping: thread = (oc, row-pair)
  const bool act2 = t < 350;
  const int oc2 = t / 7;              // 0..49
  const int rp  = t % 7;              // 0..6
  const int y0  = 2 * rp;

  for (int p = t; p < 784; p += 512) {
    xhs_l[p] = x[b * 784 + p] * 0.5f;
  }
  // zero padded buffers (halos stay zero forever; data cells rewritten
  // every step before being read)
  for (int i = t; i < 32 * 34; i += 512) pois_l[i] = 0.f;
  for (int i = t; i < 20 * 360; i += 512) sp1_l[i] = 0.f;
  for (int i = t; i < 50 * 196; i += 512) m2_l[i] = 0.f;
  for (int i = t; i < 2450; i += 512) m2s_l[i] = 0.f;
  for (int i = t; i < 20 * 196; i += 512) m1s_l[i] = 0.f;
  for (int i = t; i < 512 * 21; i += 512) m1stash[i] = 0.f;
  if (t < 352) fb[t] = 0;

  // persistent register membranes: conv1 tt=0,1 only (tt=2,3 in m1stash)
  float m1p[2][10];
#pragma unroll
  for (int i = 0; i < 10; ++i) {
    m1p[0][i] = 0.f;
    m1p[1][i] = 0.f;
  }
  __syncthreads();

  // poisson for step 0 (all threads)
  {
    uint32_t k0 = kb[0], k1 = kb[1];
    for (int p = t; p < 784; p += 512) {
      uint32_t o0, o1;
      tf2x32(k0, k1, 0u, (uint32_t)(b * 784 + p), o0, o1);
      float r = __uint_as_float(((o0 ^ o1) >> 9) | 0x3F800000u) - 1.0f;
      float v = xhs_l[p];
      pois_l[(p / 28 + 2) * 34 + (p % 28 + 2)] =
          (fabsf(v) > r) ? ((v > 0.f) ? 1.f : -1.f) : 0.f;
    }
  }
  __syncthreads();

#define LDROW(rr, d) {                                                      \
    const float2* _pr = reinterpret_cast<const float2*>(                    \
        &pois_l[(2 * qy + (rr)) * 34 + 2 * qx]);                            \
    float2 _a0 = _pr[0], _a1 = _pr[1], _a2 = _pr[2];                        \
    d[0] = _a0.x; d[1] = _a0.y; d[2] = _a1.x;                               \
    d[3] = _a1.y; d[4] = _a2.x; d[5] = _a2.y; }

#define LD4(icv, jrv, p0, p1, p2, p3) {                                     \
    const float4* _rn = reinterpret_cast<const float4*>(                    \
        sp1_l + (icv) * 360 + (y0 + (jrv)) * 20);                           \
    p0 = _rn[0]; p1 = _rn[1]; p2 = _rn[2]; p3 = _rn[3]; }

  for (int s = 0; s < STEPS; ++s) {
    // ---- P1: conv1 (10 oc of this half) + fire + pool1 + fire ----
    if (act1) {
      float rA[6], rB[6];
      LDROW(0, rA)
      LDROW(1, rB)
      float acc[4][10];
#pragma unroll
      for (int tt = 0; tt < 4; ++tt)
#pragma unroll
        for (int i = 0; i < 10; ++i) acc[tt][i] = 0.f;
#pragma unroll
      for (int ky = 0; ky < 5; ++ky) {
        // rA = padded row 2qy+ky (rows for tt 0,1), rB = row 2qy+ky+1
#pragma unroll
        for (int kx = 0; kx < 5; ++kx) {
#pragma unroll
          for (int i = 0; i < 10; ++i) {
            float w = w1[(ohu * 10 + i) * 25 + ky * 5 + kx];
            acc[0][i] += w * rA[kx];
            acc[1][i] += w * rA[kx + 1];
            acc[2][i] += w * rB[kx];
            acc[3][i] += w * rB[kx + 1];
          }
        }
        if (ky < 4) {
#pragma unroll
          for (int j = 0; j < 6; ++j) rA[j] = rB[j];
          LDROW(ky + 2, rB)
        }
      }
#pragma unroll
      for (int i = 0; i < 10; ++i) {
        float s4[4];
        // tt = 0,1: register membranes
#pragma unroll
        for (int tt = 0; tt < 2; ++tt) {
          float m = m1p[tt][i] + acc[tt][i];
          float sp = 0.f;
          if (m > 1.0f) { sp = 1.f; m = 0.f; }
          m1p[tt][i] = m;
          s4[tt] = sp;
        }
        // tt = 2,3: LDS-stashed membranes (thread-exclusive slab)
        {
          float m = m1stash[t * 21 + i] + acc[2][i];
          float sp = 0.f;
          if (m > 1.0f) { sp = 1.f; m = 0.f; }
          m1stash[t * 21 + i] = m;
          s4[2] = sp;
        }
        {
          float m = m1stash[t * 21 + 10 + i] + acc[3][i];
          float sp = 0.f;
          if (m > 1.0f) { sp = 1.f; m = 0.f; }
          m1stash[t * 21 + 10 + i] = m;
          s4[3] = sp;
        }
        float a = 0.25f * (((s4[0] + s4[1]) + s4[2]) + s4[3]);
        int mi = (ohu * 10 + i) * 196 + lq;
        float mm = m1s_l[mi] + a;
        float spp = 0.f;
        if (mm > 0.75f) { spp = 1.f; mm = 0.f; }
        m1s_l[mi] = mm;
        sp1_l[(ohu * 10 + i) * 360 + (qy + 2) * 20 + (qx + 2)] = spp;
      }
    }
    __syncthreads();

    // ---- P2: conv2 xx-packed pipeline + fused pool2; poisson on 6,7 ----
    if (act2) {
      f2 a0[7], a1[7];
#pragma unroll
      for (int j = 0; j < 7; ++j) { a0[j] = f2{0.f, 0.f}; a1[j] = f2{0.f, 0.f}; }
      float4 A0, A1, A2, A3, B0, B1, B2, B3;
      // row prologue (ic=0 rows jr0, jr1)
      LD4(0, 0, A0, A1, A2, A3)
      LD4(0, 1, B0, B1, B2, B3)
#pragma unroll 1
      for (int ic = 0; ic < 20; ++ic) {
        const int icn = (ic < 19) ? ic + 1 : 19;
        float wv[28];
        {
          const float4* wb4 =
              reinterpret_cast<const float4*>(wT2 + oc2 * 560 + ic * 28);
#pragma unroll
          for (int j = 0; j < 7; ++j) {
            float4 q = wb4[j];
            wv[4 * j]     = q.x;
            wv[4 * j + 1] = q.y;
            wv[4 * j + 2] = q.z;
            wv[4 * j + 3] = q.w;
          }
        }
        p2x<0>(A0, A1, A2, A3, wv, a0, a1);          // jr0
        LD4(ic, 2, A0, A1, A2, A3)
        __builtin_amdgcn_sched_barrier(0);
        p2x<1>(B0, B1, B2, B3, wv, a0, a1);          // jr1
        LD4(ic, 3, B0, B1, B2, B3)
        __builtin_amdgcn_sched_barrier(0);
        p2x<2>(A0, A1, A2, A3, wv, a0, a1);          // jr2
        LD4(ic, 4, A0, A1, A2, A3)
        __builtin_amdgcn_sched_barrier(0);
        p2x<3>(B0, B1, B2, B3, wv, a0, a1);          // jr3
        LD4(ic, 5, B0, B1, B2, B3)
        __builtin_amdgcn_sched_barrier(0);
        p2x<4>(A0, A1, A2, A3, wv, a0, a1);          // jr4
        LD4(icn, 0, A0, A1, A2, A3)
        __builtin_amdgcn_sched_barrier(0);
        p2x<5>(B0, B1, B2, B3, wv, a0, a1);          // jr5
        LD4(icn, 1, B0, B1, B2, B3)
        __builtin_amdgcn_sched_barrier(0);
      }
      // fire (row y0 then y0+1, xx asc — same per-element order as before)
      float f0[14], f1[14];
#pragma unroll
      for (int j = 0; j < 7; ++j) {
        {
          int li = oc2 * 196 + y0 * 14 + 2 * j;
          float m = m2_l[li] + a0[j].x;
          float sp = 0.f;
          if (m > 1.0f) { sp = 1.f; m = 0.f; }
          m2_l[li] = m;
          f0[2 * j] = sp;
        }
        {
          int li = oc2 * 196 + y0 * 14 + 2 * j + 1;
          float m = m2_l[li] + a0[j].y;
          float sp = 0.f;
          if (m > 1.0f) { sp = 1.f; m = 0.f; }
          m2_l[li] = m;
          f0[2 * j + 1] = sp;
        }
      }
#pragma unroll
      for (int j = 0; j < 7; ++j) {
        {
          int li = oc2 * 196 + (y0 + 1) * 14 + 2 * j;
          float m = m2_l[li] + a1[j].x;
          float sp = 0.f;
          if (m > 1.0f) { sp = 1.f; m = 0.f; }
          m2_l[li] = m;
          f1[2 * j] = sp;
        }
        {
          int li = oc2 * 196 + (y0 + 1) * 14 + 2 * j + 1;
          float m = m2_l[li] + a1[j].y;
          float sp = 0.f;
          if (m > 1.0f) { sp = 1.f; m = 0.f; }
          m2_l[li] = m;
          f1[2 * j + 1] = sp;
        }
      }
      // fused pool2 + fire (this thread owns pool row yo=rp of oc2)
      uint32_t byte = 0;
#pragma unroll
      for (int xo = 0; xo < 7; ++xo) {
        float a = 0.25f * (((f0[2 * xo] + f0[2 * xo + 1]) + f1[2 * xo]) +
                           f1[2 * xo + 1]);
        int e = oc2 * 49 + rp * 7 + xo;
        float m = m2s_l[e] + a;
        uint32_t bit = 0;
        if (m > 0.75f) { bit = 1; m = 0.f; }
        m2s_l[e] = m;
        byte |= bit << xo;
      }
      fb[t] = (uint8_t)byte;
    } else if (t >= 384) {
      // poisson for step s+1 under P2's shadow (waves 6,7 idle in P2)
      if (s + 1 < STEPS) {
        uint32_t k0 = kb[2 * (s + 1)], k1 = kb[2 * (s + 1) + 1];
        for (int p = t - 384; p < 784; p += 128) {
          uint32_t o0, o1;
          tf2x32(k0, k1, 0u, (uint32_t)(b * 784 + p), o0, o1);
          float r = __uint_as_float(((o0 ^ o1) >> 9) | 0x3F800000u) - 1.0f;
          float v = xhs_l[p];
          pois_l[(p / 28 + 2) * 34 + (p % 28 + 2)] =
              (fabsf(v) > r) ? ((v > 0.f) ? 1.f : -1.f) : 0.f;
        }
      }
    }
    __syncthreads();

    // ---- word assembly: bit e of sp2 stream = fb[e/7] bit (e%7) ----
    if (t < 77) {
      int j0 = (32 * t) / 7;
      uint64_t accw = 0;
#pragma unroll
      for (int jj = 0; jj < 6; ++jj) {
        int j = j0 + jj;
        uint32_t bv = (j < 350) ? (uint32_t)fb[j] : 0u;
        accw |= (uint64_t)bv << (7 * j - 32 * t + 6);
      }
      sp2g[b * 7700 + s * 77 + t] = (uint32_t)(accw >> 6);
    }
    // no barrier: next-step P1 writes don't conflict with assembly reads
  }
#undef LDROW
#undef LD4
}

// ---------------------------------------------------------------------------
// fc0 (R14-proven): block = sample, lane = neuron; wave-uniform ctz over
// spike bits; acc += wf0T[k][n] coalesced; k ascending -> bit-identical.
// ---------------------------------------------------------------------------
__global__ __launch_bounds__(256) void fc0f_k(
    const uint32_t* __restrict__ sp2g, const float* __restrict__ wf0T,
    float* __restrict__ Tf0g) {
  __shared__ uint32_t mk[77];
  const int b = blockIdx.x;
  const int n = threadIdx.x;
  float m = 0.f, T = 0.f;
  for (int s = 0; s < STEPS; ++s) {
    __syncthreads();
    if (n < 77) mk[n] = sp2g[b * 7700 + s * 77 + n];
    __syncthreads();
    float acc = 0.f;
    for (int d = 0; d < 77; ++d) {
      uint32_t um = mk[d];
      while (um) {
        int j = __builtin_ctz(um);
        um &= um - 1;
        acc += wf0T[((d << 5) + j) * 256 + n];
      }
    }
    m += acc;
    if (m > 1.0f) { T += 1.f; m = 0.f; }
  }
  if (n < 200) Tf0g[b * 200 + n] = T;
}

// ---------------------------------------------------------------------------
// final: out[b][i] = (Tf0[b][:] . wf1[i][:]) / 1 / 100   (j ascending)
// ---------------------------------------------------------------------------
__global__ void fc1_k(const float* __restrict__ Tf0,
                      const float* __restrict__ wf1,
                      float* __restrict__ out) {
  int idx = blockIdx.x * blockDim.x + threadIdx.x;
  if (idx >= 5120) return;
  int b = idx / 10, i = idx % 10;
  float a = 0.f;
  for (int j = 0; j < 200; ++j) a += Tf0[b * 200 + j] * wf1[i * 200 + j];
  out[idx] = (a / 1.0f) / 100.0f;
}

// ---------------------------------------------------------------------------
extern "C" void kernel_launch(void* const* d_in, const int* in_sizes, int n_in,
                              void* d_out, int out_size, void* d_ws, size_t ws_size,
                              hipStream_t stream) {
  (void)in_sizes; (void)n_in; (void)out_size; (void)ws_size;
  const float* x   = (const float*)d_in[0];
  const float* w1  = (const float*)d_in[1];
  const float* w2  = (const float*)d_in[2];
  const float* wf0 = (const float*)d_in[3];
  const float* wf1 = (const float*)d_in[4];
  float* out = (float*)d_out;
  char* ws = (char*)d_ws;

  // workspace: Tf0 | wT2 | keys | wf0T | sp2 bitmask  (~18.9 MB)
  const size_t tf0_b  = 512ull * 200 * 4;
  const size_t wt_b   = 50ull * 560 * 4;   // 112000 B
  const size_t key_b  = 1024;
  const size_t wf0t_b = 2450ull * 256 * 4;
  float*    Tf0g = (float*)ws;
  float*    wT2  = (float*)(ws + tf0_b);
  uint32_t* kb   = (uint32_t*)(ws + tf0_b + wt_b);
  float*    wf0T = (float*)(ws + tf0_b + wt_b + key_b);
  uint32_t* sp2g = (uint32_t*)(ws + tf0_b + wt_b + key_b + wf0t_b);

  keys_k<<<1, 128, 0, stream>>>(kb);
  wt_k<<<110, 256, 0, stream>>>(w2, wT2);
  wf0t_k<<<2450, 256, 0, stream>>>(wf0, wf0T);
  step_all_k<<<512, 512, 0, stream>>>(x, w1, wT2, kb, sp2g);
  fc0f_k<<<512, 256, 0, stream>>>(sp2g, wf0T, Tf0g);
  fc1_k<<<20, 256, 0, stream>>>(Tf0g, wf1, out);
}